// Round 1
// 3069.389 us; speedup vs baseline: 1.1569x; 1.1569x over previous
//
#include <hip/hip_runtime.h>
#include <cstdint>
#include <cstddef>

// ---------------------------------------------------------------------------
// EnhancedRNN (attention LSTM captioner). B=64, L=196, FEAT=512, T=32,
// H=512, D=512, V=32000.
//
// Round 5: (1) persistent single-kernel step loop (64 blocks x 512 threads,
// manual device-scope grid barrier, c-state in registers, bf16-packed Wd for
// coalesced dec-proj, XOR-swizzled MFMA staging) replacing the 63-dispatch
// serialized attn/gates loop — removes per-step launch + L2 flush/re-cold.
// (2) XCD-chunked m-fastest swizzle on the fc GEMM so each XCD keeps its Wf
// N-slice L2-resident across M-tiles (FETCH was 8x Wf).
// ---------------------------------------------------------------------------

typedef unsigned short u16;
typedef short  s16x8  __attribute__((ext_vector_type(8)));
typedef __bf16 bf16x8 __attribute__((ext_vector_type(8)));
typedef float  f32x4  __attribute__((ext_vector_type(4)));

__device__ __forceinline__ float bf2f(u16 u) {
  union { unsigned int i; float f; } x; x.i = ((unsigned int)u) << 16; return x.f;
}
__device__ __forceinline__ u16 f2bf(float f) {
  union { float f; unsigned int i; } x; x.f = f;
  unsigned int u = x.i;
  return (u16)((u + 0x7fffu + ((u >> 16) & 1u)) >> 16);   // RNE
}
__device__ __forceinline__ float fsig(float x) { return 1.f / (1.f + __expf(-x)); }
__device__ __forceinline__ float ftanh(float x) { float e = __expf(2.f * x); return 1.f - 2.f / (e + 1.f); }

__device__ __forceinline__ bf16x8 lds_frag(const u16* p) {
  s16x8 r = *(const s16x8*)p;
  return __builtin_bit_cast(bf16x8, r);
}

// flag-aware scalar load (input tensors may be fp32 or bf16)
__device__ __forceinline__ float ldf(const void* p, size_t idx, int f32) {
  return f32 ? ((const float*)p)[idx] : bf2f(((const u16*)p)[idx]);
}
// flag-aware 8-element load -> bf16 bits (for LDS staging)
__device__ __forceinline__ s16x8 ld8(const void* p, size_t idx, int f32) {
  if (f32) {
    f32x4 a = *(const f32x4*)((const float*)p + idx);
    f32x4 b = *(const f32x4*)((const float*)p + idx + 4);
    s16x8 r;
    r[0] = (short)f2bf(a[0]); r[1] = (short)f2bf(a[1]);
    r[2] = (short)f2bf(a[2]); r[3] = (short)f2bf(a[3]);
    r[4] = (short)f2bf(b[0]); r[5] = (short)f2bf(b[1]);
    r[6] = (short)f2bf(b[2]); r[7] = (short)f2bf(b[3]);
    return r;
  }
  return *(const s16x8*)((const u16*)p + idx);
}

// ---------------------------------------------------------------------------
// Dtype detect (1 = fp32, 0 = bf16). Also zeroes the grid-barrier counter.
// ---------------------------------------------------------------------------
__global__ void detect_kernel(const unsigned int* __restrict__ w, int* __restrict__ flagp,
                              unsigned* __restrict__ barp) {
  __shared__ int votes[256];
  if (threadIdx.x == 0) *barp = 0u;
  int v = 0;
#pragma unroll
  for (int i = 0; i < 4; ++i) {
    unsigned int x = w[threadIdx.x * 4 + i];
    int e = (x >> 7) & 0xFF;
    v += (e >= 100 && e <= 135) ? 1 : 0;
  }
  votes[threadIdx.x] = v;
  __syncthreads();
  for (int s = 128; s; s >>= 1) {
    if (threadIdx.x < s) votes[threadIdx.x] += votes[threadIdx.x + s];
    __syncthreads();
  }
  if (threadIdx.x == 0) flagp[0] = (votes[0] < 512) ? 1 : 0;
}

// ---------------------------------------------------------------------------
// bt-GEMM: C[m,n] = sum_k A[m,k]*B[n,k] + bias[n].
// swz=1: bijective XCD-chunked remap (bid%8 -> XCD), m-fastest within XCD so
// each XCD keeps one B N-slice L2-resident across all M-tiles.
// ---------------------------------------------------------------------------
__global__ __launch_bounds__(256, 2) void gemm_bt(const void* __restrict__ A,
                                                  const void* __restrict__ Bm,
                                                  const void* __restrict__ bias,
                                                  void* __restrict__ Cout,
                                                  int N, int K,
                                                  const int* __restrict__ flagp,
                                                  int aMode, int bMode,
                                                  int biasMode, int outMode,
                                                  int swz) {
  const int fg = flagp ? flagp[0] : 0;
  const int af32 = (aMode == 1) || (aMode == 2 && fg);
  const int bf32 = (bMode == 1) || (bMode == 2 && fg);
  const int biasf32 = (biasMode == 1) || (biasMode == 2 && fg);
  const int of32 = (outMode == 1) || (outMode == 2 && fg);

  int bx = blockIdx.x, by = blockIdx.y;
  if (swz) {
    const int nx = gridDim.x, ny = gridDim.y;
    const int nwg = nx * ny;
    const int orig = by * nx + bx;
    const int q = nwg >> 3, r = nwg & 7;
    const int xcd = orig & 7, s = orig >> 3;
    const int wg = (xcd < r ? xcd * (q + 1) : r * (q + 1) + (xcd - r) * q) + s;
    by = wg % ny;          // m-fastest within each XCD's contiguous chunk
    bx = wg / ny;
  }

  __shared__ __align__(16) u16 As[128 * 64];
  __shared__ __align__(16) u16 Bs[128 * 64];
  const int tid = threadIdx.x;
  const int w = tid >> 6, lane = tid & 63;
  const int lm = lane & 15, quad = lane >> 4;
  const int tm0 = by * 128, tn0 = bx * 128;
  const int wm = (w >> 1) * 64, wn = (w & 1) * 64;
  const int srow = tid >> 3, schunk = tid & 7;   // 32 rows x 8 chunks per pass

  f32x4 acc[4][4] = {};

  for (int kt = 0; kt < K; kt += 64) {
    s16x8 ra[4], rb[4];
#pragma unroll
    for (int i = 0; i < 4; ++i) {
      int r = i * 32 + srow;
      ra[i] = ld8(A, (size_t)(tm0 + r) * K + kt + schunk * 8, af32);
      rb[i] = ld8(Bm, (size_t)(tn0 + r) * K + kt + schunk * 8, bf32);
    }
    __syncthreads();                      // prior iteration's LDS reads done
#pragma unroll
    for (int i = 0; i < 4; ++i) {
      int r = i * 32 + srow;
      *(s16x8*)(As + r * 64 + schunk * 8) = ra[i];
      *(s16x8*)(Bs + r * 64 + schunk * 8) = rb[i];
    }
    __syncthreads();
#pragma unroll
    for (int ks = 0; ks < 2; ++ks) {
      bf16x8 af[4], bfr[4];
#pragma unroll
      for (int mi = 0; mi < 4; ++mi)
        af[mi] = lds_frag(&As[(wm + mi * 16 + lm) * 64 + (ks * 4 + quad) * 8]);
#pragma unroll
      for (int ni = 0; ni < 4; ++ni)
        bfr[ni] = lds_frag(&Bs[(wn + ni * 16 + lm) * 64 + (ks * 4 + quad) * 8]);
#pragma unroll
      for (int mi = 0; mi < 4; ++mi)
#pragma unroll
        for (int ni = 0; ni < 4; ++ni)
          acc[mi][ni] = __builtin_amdgcn_mfma_f32_16x16x32_bf16(af[mi], bfr[ni], acc[mi][ni], 0, 0, 0);
    }
  }

#pragma unroll
  for (int mi = 0; mi < 4; ++mi)
#pragma unroll
    for (int ni = 0; ni < 4; ++ni) {
      int col = tn0 + wn + ni * 16 + lm;
      float bv = ldf(bias, col, biasf32);
#pragma unroll
      for (int r = 0; r < 4; ++r) {
        int row = tm0 + wm + mi * 16 + quad * 4 + r;   // C/D: col=lane&15, row=quad*4+reg
        float v = acc[mi][ni][r] + bv;
        if (of32) ((float*)Cout)[(size_t)row * N + col] = v;
        else      ((u16*)Cout)[(size_t)row * N + col] = f2bf(v);
      }
    }
}

// ---------------------------------------------------------------------------
// Pack/precompute: gate-interleaved weight packing (jp = k*4 + gate), combined
// LSTM bias, emb gather, and WdP: Wd repacked bf16 as [k/8][j][8] so the
// dec-projection reads 16B/lane coalesced.
// ---------------------------------------------------------------------------
__global__ void pack_kernel(const int* __restrict__ caps, const void* __restrict__ embed,
                            const void* __restrict__ Wih, const void* __restrict__ Whh,
                            const void* __restrict__ bih, const void* __restrict__ bhh,
                            const void* __restrict__ Wd,
                            u16* __restrict__ WiheP, u16* __restrict__ W2p,
                            float* __restrict__ bias2, u16* __restrict__ embA,
                            u16* __restrict__ WdP,
                            const int* __restrict__ flagp) {
  const int fg = flagp[0];
  const int total = 4458496;
  for (int idx = blockIdx.x * blockDim.x + threadIdx.x; idx < total; idx += gridDim.x * blockDim.x) {
    if (idx < 1048576) {                       // WiheP[2048][512] (emb half of W_ih)
      int jp = idx >> 9, kk = idx & 511;
      int j = (jp & 3) * 512 + (jp >> 2);      // jp = k*4+gate -> torch row j = gate*512+k
      WiheP[idx] = f2bf(ldf(Wih, (size_t)j * 1024 + kk, fg));
    } else if (idx < 3145728) {                // W2p[2048][1024] = [Wih_ctx | Whh]
      int q = idx - 1048576;
      int jp = q >> 10, kk = q & 1023;
      int j = (jp & 3) * 512 + (jp >> 2);
      float v = (kk < 512) ? ldf(Wih, (size_t)j * 1024 + 512 + kk, fg)
                           : ldf(Whh, (size_t)j * 512 + (kk - 512), fg);
      W2p[q] = f2bf(v);
    } else if (idx < 3147776) {                // bias2 (packed order)
      int jp = idx - 3145728;
      int j = (jp & 3) * 512 + (jp >> 2);
      bias2[jp] = ldf(bih, j, fg) + ldf(bhh, j, fg);
    } else if (idx < 4196352) {                // embA[2048][512], row m = b*32+t
      int q = idx - 3147776;
      int m = q >> 9, kk = q & 511;
      embA[q] = f2bf(ldf(embed, (size_t)caps[m] * 512 + kk, fg));
    } else {                                   // WdP[(k8*512+j)*8+jj] = Wd[j][k8*8+jj]
      int q = idx - 4196352;
      int jj = q & 7, j = (q >> 3) & 511, k8 = q >> 12;
      WdP[q] = f2bf(ldf(Wd, (size_t)j * 512 + k8 * 8 + jj, fg));
    }
  }
}

// init: ctx0 = mean_l(enc) into xcat0 ctx-half; h-half of xcat0 = 0.
__global__ void init_kernel(const void* __restrict__ enc, u16* __restrict__ xcat0,
                            const int* __restrict__ flagp) {
  const int fg = flagp[0];
  int i = blockIdx.x * blockDim.x + threadIdx.x;      // 65536 threads
  if (i < 32768) {
    int b = i >> 9, f = i & 511;
    size_t base = (size_t)b * 196 * 512 + f;
    float s = 0.f;
    for (int l = 0; l < 196; ++l) s += ldf(enc, base + (size_t)l * 512, fg);
    xcat0[b * 1024 + f] = f2bf(s * (1.f / 196.f));
  } else {
    int j = i - 32768;
    int b = j >> 9, k = j & 511;
    xcat0[b * 1024 + 512 + k] = 0;                    // bf16 +0
  }
}

// ---------------------------------------------------------------------------
// Persistent step loop: 64 blocks x 512 threads, all co-resident (1 block/CU
// guaranteed: 64 <= 256 CUs, LDS ~60 KB, 8 waves). Manual grid barrier with
// agent-scope release/acquire fences (cross-XCD visibility of xbuf writes).
// Block b: attention for batch b (phase A). Block jb: gate slice
// jp in [jb*32, jb*32+32) for all 64 batches (phase B). c-state lives in one
// register per thread (thread <-> (b, kg) fixed across t).
// ---------------------------------------------------------------------------
struct __align__(16) LoopSmem {
  union {
    struct { u16 As[64 * 256]; u16 Bs[32 * 256]; float gf[64 * 33 + 4]; } b;  // ~57.3 KB
    struct { float hb[512]; float decb[512]; float sc[200]; float red[2]; } a;
  } u;
  float vb[512];
  float bdv[512];
};

__device__ __forceinline__ void gsync(unsigned* bar, unsigned& ph) {
  __syncthreads();                                  // drains vmcnt for all waves
  if (threadIdx.x == 0) {
    __builtin_amdgcn_fence(__ATOMIC_RELEASE, "agent");   // writeback dirty L2
    ++ph;
    atomicAdd(bar, 1u);
    const unsigned target = 64u * ph;
    while (__hip_atomic_load(bar, __ATOMIC_ACQUIRE, __HIP_MEMORY_SCOPE_AGENT) < target)
      __builtin_amdgcn_s_sleep(1);
    __builtin_amdgcn_fence(__ATOMIC_ACQUIRE, "agent");   // invalidate stale L1/L2
  }
  __syncthreads();
}

// XOR swizzle for 256-u16-stride LDS tiles (16B granularity, rows mod 8)
__device__ __forceinline__ int swzA(int row, int colu) {
  return (row * 512 + colu * 2) ^ ((row & 7) << 4);
}

__global__ __launch_bounds__(512, 2) void loop_kernel(
    const u16* __restrict__ encp, const u16* __restrict__ WdP,
    const void* __restrict__ bd, const void* __restrict__ vw,
    const u16* __restrict__ W2p, const float* __restrict__ embp,
    const void* __restrict__ enc, u16* xbuf,
    u16* __restrict__ hs, unsigned* bar, const int* __restrict__ flagp) {
  __shared__ LoopSmem sm;
  const int fg = flagp[0];
  const int tid = threadIdx.x;
  const int blk = blockIdx.x;
  const int w = tid >> 6, lane = tid & 63;
  const int lm = lane & 15, quad = lane >> 4;
  const int mi = w >> 1, ni = w & 1;          // wave -> (batch-tile, jp-tile)
  const int gb = tid >> 3, gkl = tid & 7;     // pointwise: thread -> (b, kg-local)

  sm.vb[tid]  = ldf(vw, tid, fg);
  sm.bdv[tid] = ldf(bd, tid, fg);
  float c_reg = 0.f;                          // LSTM cell state for (gb, blk*8+gkl)
  unsigned ph = 0;

  for (int t = 0; t < 32; ++t) {
    u16* xin  = xbuf + (size_t)(t & 1) * 65536;        // [64][ctx|h] this step
    u16* hout = xbuf + (size_t)((t + 1) & 1) * 65536;  // h written for next step

    if (t > 0) {
      // ---------------- phase A: attention for batch blk ----------------
      sm.u.a.hb[tid] = bf2f(xin[blk * 1024 + 512 + tid]);
      __syncthreads();
      { // dec[j=tid] = bd[j] + sum_k Wd[j,k] h[k], WdP coalesced 16B/lane
        float a = sm.bdv[tid];
        const u16* wp = WdP + (size_t)tid * 8;
#pragma unroll 4
        for (int k8 = 0; k8 < 64; ++k8) {
          s16x8 v = *(const s16x8*)(wp + (size_t)k8 * 4096);
#pragma unroll
          for (int j = 0; j < 8; ++j) a += bf2f((u16)v[j]) * sm.u.a.hb[k8 * 8 + j];
        }
        sm.u.a.decb[tid] = a;
      }
      __syncthreads();
      // scores: one wave per l row (8 waves round-robin); v_b softmax-invariant
      for (int l = w; l < 196; l += 8) {
        s16x8 ev = *(const s16x8*)(encp + ((size_t)(blk * 196 + l)) * 512 + lane * 8);
        float s = 0.f;
#pragma unroll
        for (int j = 0; j < 8; ++j) {
          float x = bf2f((u16)ev[j]) + sm.u.a.decb[lane * 8 + j];
          s += sm.vb[lane * 8 + j] * ftanh(x);
        }
#pragma unroll
        for (int o = 32; o; o >>= 1) s += __shfl_xor(s, o, 64);
        if (lane == 0) sm.u.a.sc[l] = s;
      }
      __syncthreads();
      if (tid < 64) {
        float m = -1e30f;
        for (int l = tid; l < 196; l += 64) m = fmaxf(m, sm.u.a.sc[l]);
#pragma unroll
        for (int o = 32; o; o >>= 1) m = fmaxf(m, __shfl_xor(m, o, 64));
        if (tid == 0) sm.u.a.red[0] = m;
      }
      __syncthreads();
      if (tid < 196) sm.u.a.sc[tid] = __expf(sm.u.a.sc[tid] - sm.u.a.red[0]);
      __syncthreads();
      if (tid < 64) {
        float s = 0.f;
        for (int l = tid; l < 196; l += 64) s += sm.u.a.sc[l];
#pragma unroll
        for (int o = 32; o; o >>= 1) s += __shfl_xor(s, o, 64);
        if (tid == 0) sm.u.a.red[1] = 1.f / s;
      }
      __syncthreads();
      { // context: thread f, coalesced over f per l
        float a = 0.f;
        size_t base = (size_t)blk * 196 * 512 + tid;
#pragma unroll 4
        for (int l = 0; l < 196; ++l) a += sm.u.a.sc[l] * ldf(enc, base + (size_t)l * 512, fg);
        a *= sm.u.a.red[1];
        xin[blk * 1024 + tid] = f2bf(a);
      }
      gsync(bar, ph);   // all ctx visible before gates read xin
    }

    // ---------------- phase B: gates, jp slice [blk*32, blk*32+32) ----------------
    f32x4 acc = {};
    const int sra = tid >> 3, sca = (tid & 7) * 32;    // A stage: 64 rows x 8 chunks
    const int srb = tid >> 4, scb = (tid & 15) * 16;   // B stage: 32 rows x 16 chunks
    for (int kt = 0; kt < 1024; kt += 256) {
      s16x8 ra0 = *(const s16x8*)(xin + (size_t)sra * 1024 + kt + sca);
      s16x8 ra1 = *(const s16x8*)(xin + (size_t)sra * 1024 + kt + sca + 8);
      s16x8 ra2 = *(const s16x8*)(xin + (size_t)sra * 1024 + kt + sca + 16);
      s16x8 ra3 = *(const s16x8*)(xin + (size_t)sra * 1024 + kt + sca + 24);
      s16x8 rb0 = *(const s16x8*)(W2p + (size_t)(blk * 32 + srb) * 1024 + kt + scb);
      s16x8 rb1 = *(const s16x8*)(W2p + (size_t)(blk * 32 + srb) * 1024 + kt + scb + 8);
      __syncthreads();                        // prior LDS readers done
      *(s16x8*)((char*)sm.u.b.As + swzA(sra, sca))      = ra0;
      *(s16x8*)((char*)sm.u.b.As + swzA(sra, sca + 8))  = ra1;
      *(s16x8*)((char*)sm.u.b.As + swzA(sra, sca + 16)) = ra2;
      *(s16x8*)((char*)sm.u.b.As + swzA(sra, sca + 24)) = ra3;
      *(s16x8*)((char*)sm.u.b.Bs + swzA(srb, scb))      = rb0;
      *(s16x8*)((char*)sm.u.b.Bs + swzA(srb, scb + 8))  = rb1;
      __syncthreads();
#pragma unroll
      for (int ks = 0; ks < 8; ++ks) {
        bf16x8 af = lds_frag((const u16*)((const char*)sm.u.b.As + swzA(mi * 16 + lm, ks * 32 + quad * 8)));
        bf16x8 bf = lds_frag((const u16*)((const char*)sm.u.b.Bs + swzA(ni * 16 + lm, ks * 32 + quad * 8)));
        acc = __builtin_amdgcn_mfma_f32_16x16x32_bf16(af, bf, acc, 0, 0, 0);
      }
    }
#pragma unroll
    for (int r = 0; r < 4; ++r)              // C/D: col=lane&15, row=quad*4+reg
      sm.u.b.gf[(mi * 16 + quad * 4 + r) * 33 + ni * 16 + lm] = acc[r];
    __syncthreads();
    { // LSTM pointwise: thread -> (b=gb, kg=blk*8+gkl); c in register
      const int kg = blk * 8 + gkl;
      const int m = gb * 32 + t;
      const float* gp = &sm.u.b.gf[gb * 33 + gkl * 4];
      f32x4 ep = *(const f32x4*)(embp + (size_t)m * 2048 + blk * 32 + gkl * 4);
      float gi = gp[0] + ep[0];
      float gf_ = gp[1] + ep[1];
      float gg = gp[2] + ep[2];
      float go = gp[3] + ep[3];
      c_reg = fsig(gf_) * c_reg + fsig(gi) * ftanh(gg);
      float h2 = fsig(go) * ftanh(c_reg);
      u16 hb = f2bf(h2);
      hout[gb * 1024 + 512 + kg] = hb;
      hs[(size_t)m * 512 + kg] = hb;
    }
    if (t < 31) gsync(bar, ph);   // h visible before next step's attention
  }
}

// ---------------------------------------------------------------------------
// Scratch layout inside d_out (>= 262 MB; all dead before the final fc GEMM):
// ---------------------------------------------------------------------------
static constexpr size_t OFF_ENCP = 0;                       // u16 [12544][512]
static constexpr size_t OFF_EMBP = 16777216;                // f32 [2048][2048]
static constexpr size_t OFF_EMBA = 33554432;                // u16 [2048][512]
static constexpr size_t OFF_WIHE = 35651584;                // u16 [2048][512]
static constexpr size_t OFF_W2P  = 37748736;                // u16 [2048][1024]
static constexpr size_t OFF_B2   = 41943040;                // f32 [2048]
static constexpr size_t OFF_XC0  = 41951232;                // u16 [2][64][1024] (ping-pong)
static constexpr size_t OFF_WDP  = 42213376;                // u16 [64][512][8] packed Wd
static constexpr size_t OFF_BAR  = 42737664;                // u32 grid-barrier counter
// d_ws: hs (u16 [2048][512] = 2 MB) + dtype flag (int).

extern "C" void kernel_launch(void* const* d_in, const int* in_sizes, int n_in,
                              void* d_out, int out_size, void* d_ws, size_t ws_size,
                              hipStream_t stream) {
  const void* enc   = d_in[0];
  const int*  caps  = (const int*)d_in[1];
  const void* embed = d_in[2];
  const void* We    = d_in[3];
  const void* be    = d_in[4];
  const void* Wd    = d_in[5];
  const void* bd    = d_in[6];
  const void* vw    = d_in[7];
  // d_in[8] (v_b) unused: constant shift inside softmax
  const void* Wih   = d_in[9];
  const void* Whh   = d_in[10];
  const void* bih   = d_in[11];
  const void* bhh   = d_in[12];
  const void* Wf    = d_in[13];
  const void* bfv   = d_in[14];

  char* ob = (char*)d_out;
  u16*      encp   = (u16*)(ob + OFF_ENCP);
  float*    embp   = (float*)(ob + OFF_EMBP);
  u16*      embA   = (u16*)(ob + OFF_EMBA);
  u16*      WiheP  = (u16*)(ob + OFF_WIHE);
  u16*      W2p    = (u16*)(ob + OFF_W2P);
  float*    bias2  = (float*)(ob + OFF_B2);
  u16*      xbuf   = (u16*)(ob + OFF_XC0);
  u16*      WdP    = (u16*)(ob + OFF_WDP);
  unsigned* bar    = (unsigned*)(ob + OFF_BAR);
  u16*      hs     = (u16*)d_ws;
  int*      flagp  = (int*)((char*)d_ws + 2048ull * 512 * 2);

  detect_kernel<<<1, 256, 0, stream>>>((const unsigned int*)embed, flagp, bar);
  pack_kernel<<<4096, 256, 0, stream>>>(caps, embed, Wih, Whh, bih, bhh, Wd,
                                        WiheP, W2p, bias2, embA, WdP, flagp);
  init_kernel<<<256, 256, 0, stream>>>(enc, xbuf, flagp);

  // enc_proj (bf16 scratch): [12544,512] x We[512,512] + be
  gemm_bt<<<dim3(4, 98), 256, 0, stream>>>(enc, We, be, encp, 512, 512, flagp, 2, 2, 2, 0, 0);
  // embproj (fp32 scratch): [2048,512] x WiheP[2048,512] + (b_ih+b_hh)
  gemm_bt<<<dim3(16, 16), 256, 0, stream>>>(embA, WiheP, bias2, embp, 2048, 512, flagp, 0, 0, 1, 1, 0);

  // all 32 timesteps in one persistent kernel
  loop_kernel<<<64, 512, 0, stream>>>(encp, WdP, bd, vw, W2p, embp, enc, xbuf, hs, bar, flagp);

  // fc head: [2048,512] x Wf[32000,512] + bf -> d_out [B,T,V] (XCD-chunked swizzle)
  gemm_bt<<<dim3(250, 16), 256, 0, stream>>>(hs, Wf, bfv, d_out, 32000, 512, flagp, 0, 2, 2, 2, 1);
}

// Round 2
// 2997.023 us; speedup vs baseline: 1.1849x; 1.0241x over previous
//
#include <hip/hip_runtime.h>
#include <cstdint>
#include <cstddef>

// ---------------------------------------------------------------------------
// EnhancedRNN (attention LSTM captioner). B=64, L=196, FEAT=512, T=32,
// H=512, D=512, V=32000.
//
// Round 6: fence-free grid barrier. Round-5's gsync used agent-scope
// release/acquire fences which invalidate the per-XCD L2 at every barrier
// (62x) -> 640 MB refetch, latency-bound at 273 GB/s. Now the only
// cross-block data (ctx, h, barrier counter) moves via system-scope RELAXED
// atomics (sc0 sc1: bypass L1/L2, served by the coherent Infinity Cache);
// the barrier is a relaxed atomicAdd + relaxed spin with NO cache fences.
// __syncthreads() before the counter bump drains each wave's vmcnt, so all
// sc1 stores are at the coherence point before the counter moves. L2 stays
// warm with enc/encp/W2p/WdP/embp across all 32 steps.
// ---------------------------------------------------------------------------

typedef unsigned short u16;
typedef short  s16x8  __attribute__((ext_vector_type(8)));
typedef __bf16 bf16x8 __attribute__((ext_vector_type(8)));
typedef float  f32x4  __attribute__((ext_vector_type(4)));

__device__ __forceinline__ float bf2f(u16 u) {
  union { unsigned int i; float f; } x; x.i = ((unsigned int)u) << 16; return x.f;
}
__device__ __forceinline__ u16 f2bf(float f) {
  union { float f; unsigned int i; } x; x.f = f;
  unsigned int u = x.i;
  return (u16)((u + 0x7fffu + ((u >> 16) & 1u)) >> 16);   // RNE
}
__device__ __forceinline__ float fsig(float x) { return 1.f / (1.f + __expf(-x)); }
__device__ __forceinline__ float ftanh(float x) { float e = __expf(2.f * x); return 1.f - 2.f / (e + 1.f); }

__device__ __forceinline__ bf16x8 lds_frag(const u16* p) {
  s16x8 r = *(const s16x8*)p;
  return __builtin_bit_cast(bf16x8, r);
}

// flag-aware scalar load (input tensors may be fp32 or bf16)
__device__ __forceinline__ float ldf(const void* p, size_t idx, int f32) {
  return f32 ? ((const float*)p)[idx] : bf2f(((const u16*)p)[idx]);
}
// flag-aware 8-element load -> bf16 bits (for LDS staging)
__device__ __forceinline__ s16x8 ld8(const void* p, size_t idx, int f32) {
  if (f32) {
    f32x4 a = *(const f32x4*)((const float*)p + idx);
    f32x4 b = *(const f32x4*)((const float*)p + idx + 4);
    s16x8 r;
    r[0] = (short)f2bf(a[0]); r[1] = (short)f2bf(a[1]);
    r[2] = (short)f2bf(a[2]); r[3] = (short)f2bf(a[3]);
    r[4] = (short)f2bf(b[0]); r[5] = (short)f2bf(b[1]);
    r[6] = (short)f2bf(b[2]); r[7] = (short)f2bf(b[3]);
    return r;
  }
  return *(const s16x8*)((const u16*)p + idx);
}

// system-scope (coherence-point) accessors for cross-block data: lower to
// global_load/store ... sc0 sc1 (bypass L1/L2, no cache maintenance).
__device__ __forceinline__ unsigned ld32_sys(const u16* p) {
  return __hip_atomic_load((const unsigned*)p, __ATOMIC_RELAXED, __HIP_MEMORY_SCOPE_SYSTEM);
}
__device__ __forceinline__ void st32_sys(u16* p, unsigned v) {
  __hip_atomic_store((unsigned*)p, v, __ATOMIC_RELAXED, __HIP_MEMORY_SCOPE_SYSTEM);
}
__device__ __forceinline__ s16x8 ld8_sys(const u16* p) {
  union { unsigned long long q[2]; s16x8 v; } x;
  x.q[0] = __hip_atomic_load((const unsigned long long*)p, __ATOMIC_RELAXED, __HIP_MEMORY_SCOPE_SYSTEM);
  x.q[1] = __hip_atomic_load((const unsigned long long*)(p + 4), __ATOMIC_RELAXED, __HIP_MEMORY_SCOPE_SYSTEM);
  return x.v;
}

// ---------------------------------------------------------------------------
// Dtype detect (1 = fp32, 0 = bf16). Also zeroes the grid-barrier counter.
// ---------------------------------------------------------------------------
__global__ void detect_kernel(const unsigned int* __restrict__ w, int* __restrict__ flagp,
                              unsigned* __restrict__ barp) {
  __shared__ int votes[256];
  if (threadIdx.x == 0)
    __hip_atomic_store(barp, 0u, __ATOMIC_RELAXED, __HIP_MEMORY_SCOPE_SYSTEM);
  int v = 0;
#pragma unroll
  for (int i = 0; i < 4; ++i) {
    unsigned int x = w[threadIdx.x * 4 + i];
    int e = (x >> 7) & 0xFF;
    v += (e >= 100 && e <= 135) ? 1 : 0;
  }
  votes[threadIdx.x] = v;
  __syncthreads();
  for (int s = 128; s; s >>= 1) {
    if (threadIdx.x < s) votes[threadIdx.x] += votes[threadIdx.x + s];
    __syncthreads();
  }
  if (threadIdx.x == 0) flagp[0] = (votes[0] < 512) ? 1 : 0;
}

// ---------------------------------------------------------------------------
// bt-GEMM: C[m,n] = sum_k A[m,k]*B[n,k] + bias[n].
// swz=1: bijective XCD-chunked remap (bid%8 -> XCD), m-fastest within XCD so
// each XCD keeps one B N-slice L2-resident across M-tiles.
// ---------------------------------------------------------------------------
__global__ __launch_bounds__(256, 2) void gemm_bt(const void* __restrict__ A,
                                                  const void* __restrict__ Bm,
                                                  const void* __restrict__ bias,
                                                  void* __restrict__ Cout,
                                                  int N, int K,
                                                  const int* __restrict__ flagp,
                                                  int aMode, int bMode,
                                                  int biasMode, int outMode,
                                                  int swz) {
  const int fg = flagp ? flagp[0] : 0;
  const int af32 = (aMode == 1) || (aMode == 2 && fg);
  const int bf32 = (bMode == 1) || (bMode == 2 && fg);
  const int biasf32 = (biasMode == 1) || (biasMode == 2 && fg);
  const int of32 = (outMode == 1) || (outMode == 2 && fg);

  int bx = blockIdx.x, by = blockIdx.y;
  if (swz) {
    const int nx = gridDim.x, ny = gridDim.y;
    const int nwg = nx * ny;
    const int orig = by * nx + bx;
    const int q = nwg >> 3, r = nwg & 7;
    const int xcd = orig & 7, s = orig >> 3;
    const int wg = (xcd < r ? xcd * (q + 1) : r * (q + 1) + (xcd - r) * q) + s;
    by = wg % ny;          // m-fastest within each XCD's contiguous chunk
    bx = wg / ny;
  }

  __shared__ __align__(16) u16 As[128 * 64];
  __shared__ __align__(16) u16 Bs[128 * 64];
  const int tid = threadIdx.x;
  const int w = tid >> 6, lane = tid & 63;
  const int lm = lane & 15, quad = lane >> 4;
  const int tm0 = by * 128, tn0 = bx * 128;
  const int wm = (w >> 1) * 64, wn = (w & 1) * 64;
  const int srow = tid >> 3, schunk = tid & 7;   // 32 rows x 8 chunks per pass

  f32x4 acc[4][4] = {};

  for (int kt = 0; kt < K; kt += 64) {
    s16x8 ra[4], rb[4];
#pragma unroll
    for (int i = 0; i < 4; ++i) {
      int r = i * 32 + srow;
      ra[i] = ld8(A, (size_t)(tm0 + r) * K + kt + schunk * 8, af32);
      rb[i] = ld8(Bm, (size_t)(tn0 + r) * K + kt + schunk * 8, bf32);
    }
    __syncthreads();                      // prior iteration's LDS reads done
#pragma unroll
    for (int i = 0; i < 4; ++i) {
      int r = i * 32 + srow;
      *(s16x8*)(As + r * 64 + schunk * 8) = ra[i];
      *(s16x8*)(Bs + r * 64 + schunk * 8) = rb[i];
    }
    __syncthreads();
#pragma unroll
    for (int ks = 0; ks < 2; ++ks) {
      bf16x8 af[4], bfr[4];
#pragma unroll
      for (int mi = 0; mi < 4; ++mi)
        af[mi] = lds_frag(&As[(wm + mi * 16 + lm) * 64 + (ks * 4 + quad) * 8]);
#pragma unroll
      for (int ni = 0; ni < 4; ++ni)
        bfr[ni] = lds_frag(&Bs[(wn + ni * 16 + lm) * 64 + (ks * 4 + quad) * 8]);
#pragma unroll
      for (int mi = 0; mi < 4; ++mi)
#pragma unroll
        for (int ni = 0; ni < 4; ++ni)
          acc[mi][ni] = __builtin_amdgcn_mfma_f32_16x16x32_bf16(af[mi], bfr[ni], acc[mi][ni], 0, 0, 0);
    }
  }

#pragma unroll
  for (int mi = 0; mi < 4; ++mi)
#pragma unroll
    for (int ni = 0; ni < 4; ++ni) {
      int col = tn0 + wn + ni * 16 + lm;
      float bv = ldf(bias, col, biasf32);
#pragma unroll
      for (int r = 0; r < 4; ++r) {
        int row = tm0 + wm + mi * 16 + quad * 4 + r;   // C/D: col=lane&15, row=quad*4+reg
        float v = acc[mi][ni][r] + bv;
        if (of32) ((float*)Cout)[(size_t)row * N + col] = v;
        else      ((u16*)Cout)[(size_t)row * N + col] = f2bf(v);
      }
    }
}

// ---------------------------------------------------------------------------
// Pack/precompute: gate-interleaved weight packing (jp = k*4 + gate), combined
// LSTM bias, emb gather, and WdP: Wd repacked bf16 as [k/8][j][8] so the
// dec-projection reads 16B/lane coalesced.
// ---------------------------------------------------------------------------
__global__ void pack_kernel(const int* __restrict__ caps, const void* __restrict__ embed,
                            const void* __restrict__ Wih, const void* __restrict__ Whh,
                            const void* __restrict__ bih, const void* __restrict__ bhh,
                            const void* __restrict__ Wd,
                            u16* __restrict__ WiheP, u16* __restrict__ W2p,
                            float* __restrict__ bias2, u16* __restrict__ embA,
                            u16* __restrict__ WdP,
                            const int* __restrict__ flagp) {
  const int fg = flagp[0];
  const int total = 4458496;
  for (int idx = blockIdx.x * blockDim.x + threadIdx.x; idx < total; idx += gridDim.x * blockDim.x) {
    if (idx < 1048576) {                       // WiheP[2048][512] (emb half of W_ih)
      int jp = idx >> 9, kk = idx & 511;
      int j = (jp & 3) * 512 + (jp >> 2);      // jp = k*4+gate -> torch row j = gate*512+k
      WiheP[idx] = f2bf(ldf(Wih, (size_t)j * 1024 + kk, fg));
    } else if (idx < 3145728) {                // W2p[2048][1024] = [Wih_ctx | Whh]
      int q = idx - 1048576;
      int jp = q >> 10, kk = q & 1023;
      int j = (jp & 3) * 512 + (jp >> 2);
      float v = (kk < 512) ? ldf(Wih, (size_t)j * 1024 + 512 + kk, fg)
                           : ldf(Whh, (size_t)j * 512 + (kk - 512), fg);
      W2p[q] = f2bf(v);
    } else if (idx < 3147776) {                // bias2 (packed order)
      int jp = idx - 3145728;
      int j = (jp & 3) * 512 + (jp >> 2);
      bias2[jp] = ldf(bih, j, fg) + ldf(bhh, j, fg);
    } else if (idx < 4196352) {                // embA[2048][512], row m = b*32+t
      int q = idx - 3147776;
      int m = q >> 9, kk = q & 511;
      embA[q] = f2bf(ldf(embed, (size_t)caps[m] * 512 + kk, fg));
    } else {                                   // WdP[(k8*512+j)*8+jj] = Wd[j][k8*8+jj]
      int q = idx - 4196352;
      int jj = q & 7, j = (q >> 3) & 511, k8 = q >> 12;
      WdP[q] = f2bf(ldf(Wd, (size_t)j * 512 + k8 * 8 + jj, fg));
    }
  }
}

// init: ctx0 = mean_l(enc) into xcat0 ctx-half; h-half of xcat0 = 0.
__global__ void init_kernel(const void* __restrict__ enc, u16* __restrict__ xcat0,
                            const int* __restrict__ flagp) {
  const int fg = flagp[0];
  int i = blockIdx.x * blockDim.x + threadIdx.x;      // 65536 threads
  if (i < 32768) {
    int b = i >> 9, f = i & 511;
    size_t base = (size_t)b * 196 * 512 + f;
    float s = 0.f;
    for (int l = 0; l < 196; ++l) s += ldf(enc, base + (size_t)l * 512, fg);
    xcat0[b * 1024 + f] = f2bf(s * (1.f / 196.f));
  } else {
    int j = i - 32768;
    int b = j >> 9, k = j & 511;
    xcat0[b * 1024 + 512 + k] = 0;                    // bf16 +0
  }
}

// ---------------------------------------------------------------------------
// Persistent step loop: 64 blocks x 512 threads. Fence-free grid barrier;
// ctx/h cross-block traffic via sc0/sc1 system-scope accesses.
// ---------------------------------------------------------------------------
struct __align__(16) LoopSmem {
  union {
    struct { u16 As[64 * 256]; u16 Bs[32 * 256]; float gf[64 * 33 + 4]; } b;  // ~57.3 KB
    struct { float hb[512]; float decb[512]; float sc[200]; float red[2]; } a;
  } u;
  float vb[512];
  float bdv[512];
};

__device__ __forceinline__ void gsync(unsigned* bar, unsigned& ph) {
  __syncthreads();                                  // drains vmcnt for all waves
  if (threadIdx.x == 0) {
    ++ph;
    __hip_atomic_fetch_add(bar, 1u, __ATOMIC_RELAXED, __HIP_MEMORY_SCOPE_SYSTEM);
    const unsigned target = 64u * ph;
    while (__hip_atomic_load(bar, __ATOMIC_RELAXED, __HIP_MEMORY_SCOPE_SYSTEM) < target)
      __builtin_amdgcn_s_sleep(2);
  }
  __syncthreads();
}

// XOR swizzle for 256-u16-stride LDS tiles (16B granularity, rows mod 8)
__device__ __forceinline__ int swzA(int row, int colu) {
  return (row * 512 + colu * 2) ^ ((row & 7) << 4);
}

__global__ __launch_bounds__(512, 2) void loop_kernel(
    const u16* __restrict__ encp, const u16* __restrict__ WdP,
    const void* __restrict__ bd, const void* __restrict__ vw,
    const u16* __restrict__ W2p, const float* __restrict__ embp,
    const void* __restrict__ enc, u16* xbuf,
    u16* __restrict__ hs, unsigned* bar, const int* __restrict__ flagp) {
  __shared__ LoopSmem sm;
  const int fg = flagp[0];
  const int tid = threadIdx.x;
  const int blk = blockIdx.x;
  const int w = tid >> 6, lane = tid & 63;
  const int lm = lane & 15, quad = lane >> 4;
  const int mi = w >> 1, ni = w & 1;          // wave -> (batch-tile, jp-tile)
  const int gb = tid >> 3, gkl = tid & 7;     // pointwise: thread -> (b, kg-local)

  sm.vb[tid]  = ldf(vw, tid, fg);
  sm.bdv[tid] = ldf(bd, tid, fg);
  float c_reg = 0.f;                          // LSTM cell state for (gb, blk*8+gkl)
  unsigned ph = 0;

  for (int t = 0; t < 32; ++t) {
    u16* xin  = xbuf + (size_t)(t & 1) * 65536;        // [64][ctx|h] this step
    u16* hout = xbuf + (size_t)((t + 1) & 1) * 65536;  // h written for next step

    if (t > 0) {
      // ---------------- phase A: attention for batch blk ----------------
      if (tid < 256) {                         // h (written sc1 last step)
        unsigned q = ld32_sys(xin + blk * 1024 + 512 + 2 * tid);
        sm.u.a.hb[2 * tid]     = bf2f((u16)(q & 0xffffu));
        sm.u.a.hb[2 * tid + 1] = bf2f((u16)(q >> 16));
      }
      __syncthreads();
      { // dec[j=tid] = bd[j] + sum_k Wd[j,k] h[k], WdP coalesced 16B/lane
        float a = sm.bdv[tid];
        const u16* wp = WdP + (size_t)tid * 8;
#pragma unroll 4
        for (int k8 = 0; k8 < 64; ++k8) {
          s16x8 v = *(const s16x8*)(wp + (size_t)k8 * 4096);
#pragma unroll
          for (int j = 0; j < 8; ++j) a += bf2f((u16)v[j]) * sm.u.a.hb[k8 * 8 + j];
        }
        sm.u.a.decb[tid] = a;
      }
      __syncthreads();
      // scores: one wave per l row (8 waves round-robin); v_b softmax-invariant
      for (int l = w; l < 196; l += 8) {
        s16x8 ev = *(const s16x8*)(encp + ((size_t)(blk * 196 + l)) * 512 + lane * 8);
        float s = 0.f;
#pragma unroll
        for (int j = 0; j < 8; ++j) {
          float x = bf2f((u16)ev[j]) + sm.u.a.decb[lane * 8 + j];
          s += sm.vb[lane * 8 + j] * ftanh(x);
        }
#pragma unroll
        for (int o = 32; o; o >>= 1) s += __shfl_xor(s, o, 64);
        if (lane == 0) sm.u.a.sc[l] = s;
      }
      __syncthreads();
      if (tid < 64) {
        float m = -1e30f;
        for (int l = tid; l < 196; l += 64) m = fmaxf(m, sm.u.a.sc[l]);
#pragma unroll
        for (int o = 32; o; o >>= 1) m = fmaxf(m, __shfl_xor(m, o, 64));
        if (tid == 0) sm.u.a.red[0] = m;
      }
      __syncthreads();
      if (tid < 196) sm.u.a.sc[tid] = __expf(sm.u.a.sc[tid] - sm.u.a.red[0]);
      __syncthreads();
      if (tid < 64) {
        float s = 0.f;
        for (int l = tid; l < 196; l += 64) s += sm.u.a.sc[l];
#pragma unroll
        for (int o = 32; o; o >>= 1) s += __shfl_xor(s, o, 64);
        if (tid == 0) sm.u.a.red[1] = 1.f / s;
      }
      __syncthreads();
      { // context: thread f, coalesced over f per l; ctx store paired u32 sc1
        float a = 0.f;
        size_t base = (size_t)blk * 196 * 512 + tid;
#pragma unroll 4
        for (int l = 0; l < 196; ++l) a += sm.u.a.sc[l] * ldf(enc, base + (size_t)l * 512, fg);
        a *= sm.u.a.red[1];
        u16 cv = f2bf(a);
        unsigned nxt = __shfl_down((unsigned)cv, 1, 64);
        if (!(tid & 1))
          st32_sys(xin + blk * 1024 + tid, (unsigned)cv | (nxt << 16));
      }
      gsync(bar, ph);   // all ctx at coherence point before gates read xin
    }

    // ---------------- phase B: gates, jp slice [blk*32, blk*32+32) ----------------
    f32x4 acc = {};
    const int sra = tid >> 3, sca = (tid & 7) * 32;    // A stage: 64 rows x 8 chunks
    const int srb = tid >> 4, scb = (tid & 15) * 16;   // B stage: 32 rows x 16 chunks
    for (int kt = 0; kt < 1024; kt += 256) {
      s16x8 ra0 = ld8_sys(xin + (size_t)sra * 1024 + kt + sca);
      s16x8 ra1 = ld8_sys(xin + (size_t)sra * 1024 + kt + sca + 8);
      s16x8 ra2 = ld8_sys(xin + (size_t)sra * 1024 + kt + sca + 16);
      s16x8 ra3 = ld8_sys(xin + (size_t)sra * 1024 + kt + sca + 24);
      s16x8 rb0 = *(const s16x8*)(W2p + (size_t)(blk * 32 + srb) * 1024 + kt + scb);
      s16x8 rb1 = *(const s16x8*)(W2p + (size_t)(blk * 32 + srb) * 1024 + kt + scb + 8);
      __syncthreads();                        // prior LDS readers done
      *(s16x8*)((char*)sm.u.b.As + swzA(sra, sca))      = ra0;
      *(s16x8*)((char*)sm.u.b.As + swzA(sra, sca + 8))  = ra1;
      *(s16x8*)((char*)sm.u.b.As + swzA(sra, sca + 16)) = ra2;
      *(s16x8*)((char*)sm.u.b.As + swzA(sra, sca + 24)) = ra3;
      *(s16x8*)((char*)sm.u.b.Bs + swzA(srb, scb))      = rb0;
      *(s16x8*)((char*)sm.u.b.Bs + swzA(srb, scb + 8))  = rb1;
      __syncthreads();
#pragma unroll
      for (int ks = 0; ks < 8; ++ks) {
        bf16x8 af = lds_frag((const u16*)((const char*)sm.u.b.As + swzA(mi * 16 + lm, ks * 32 + quad * 8)));
        bf16x8 bf = lds_frag((const u16*)((const char*)sm.u.b.Bs + swzA(ni * 16 + lm, ks * 32 + quad * 8)));
        acc = __builtin_amdgcn_mfma_f32_16x16x32_bf16(af, bf, acc, 0, 0, 0);
      }
    }
#pragma unroll
    for (int r = 0; r < 4; ++r)              // C/D: col=lane&15, row=quad*4+reg
      sm.u.b.gf[(mi * 16 + quad * 4 + r) * 33 + ni * 16 + lm] = acc[r];
    __syncthreads();
    { // LSTM pointwise: thread -> (b=gb, kg=blk*8+gkl); c in register
      const int kg = blk * 8 + gkl;
      const int m = gb * 32 + t;
      const float* gp = &sm.u.b.gf[gb * 33 + gkl * 4];
      f32x4 ep = *(const f32x4*)(embp + (size_t)m * 2048 + blk * 32 + gkl * 4);
      float gi = gp[0] + ep[0];
      float gf_ = gp[1] + ep[1];
      float gg = gp[2] + ep[2];
      float go = gp[3] + ep[3];
      c_reg = fsig(gf_) * c_reg + fsig(gi) * ftanh(gg);
      float h2 = fsig(go) * ftanh(c_reg);
      u16 hb = f2bf(h2);
      hs[(size_t)m * 512 + kg] = hb;
      unsigned nh = __shfl_down((unsigned)hb, 1, 64);
      if (!(gkl & 1))
        st32_sys(hout + gb * 1024 + 512 + kg, (unsigned)hb | (nh << 16));
    }
    if (t < 31) gsync(bar, ph);   // h at coherence point before next attention
  }
}

// ---------------------------------------------------------------------------
// Scratch layout inside d_out (all dead before the final fc GEMM):
// ---------------------------------------------------------------------------
static constexpr size_t OFF_ENCP = 0;                       // u16 [12544][512]
static constexpr size_t OFF_EMBP = 16777216;                // f32 [2048][2048]
static constexpr size_t OFF_EMBA = 33554432;                // u16 [2048][512]
static constexpr size_t OFF_WIHE = 35651584;                // u16 [2048][512]
static constexpr size_t OFF_W2P  = 37748736;                // u16 [2048][1024]
static constexpr size_t OFF_B2   = 41943040;                // f32 [2048]
static constexpr size_t OFF_XC0  = 41951232;                // u16 [2][64][1024] (ping-pong)
static constexpr size_t OFF_WDP  = 42213376;                // u16 [64][512][8] packed Wd
static constexpr size_t OFF_BAR  = 42737664;                // u32 grid-barrier counter
// d_ws: hs (u16 [2048][512] = 2 MB) + dtype flag (int).

extern "C" void kernel_launch(void* const* d_in, const int* in_sizes, int n_in,
                              void* d_out, int out_size, void* d_ws, size_t ws_size,
                              hipStream_t stream) {
  const void* enc   = d_in[0];
  const int*  caps  = (const int*)d_in[1];
  const void* embed = d_in[2];
  const void* We    = d_in[3];
  const void* be    = d_in[4];
  const void* Wd    = d_in[5];
  const void* bd    = d_in[6];
  const void* vw    = d_in[7];
  // d_in[8] (v_b) unused: constant shift inside softmax
  const void* Wih   = d_in[9];
  const void* Whh   = d_in[10];
  const void* bih   = d_in[11];
  const void* bhh   = d_in[12];
  const void* Wf    = d_in[13];
  const void* bfv   = d_in[14];

  char* ob = (char*)d_out;
  u16*      encp   = (u16*)(ob + OFF_ENCP);
  float*    embp   = (float*)(ob + OFF_EMBP);
  u16*      embA   = (u16*)(ob + OFF_EMBA);
  u16*      WiheP  = (u16*)(ob + OFF_WIHE);
  u16*      W2p    = (u16*)(ob + OFF_W2P);
  float*    bias2  = (float*)(ob + OFF_B2);
  u16*      xbuf   = (u16*)(ob + OFF_XC0);
  u16*      WdP    = (u16*)(ob + OFF_WDP);
  unsigned* bar    = (unsigned*)(ob + OFF_BAR);
  u16*      hs     = (u16*)d_ws;
  int*      flagp  = (int*)((char*)d_ws + 2048ull * 512 * 2);

  detect_kernel<<<1, 256, 0, stream>>>((const unsigned int*)embed, flagp, bar);
  pack_kernel<<<4096, 256, 0, stream>>>(caps, embed, Wih, Whh, bih, bhh, Wd,
                                        WiheP, W2p, bias2, embA, WdP, flagp);
  init_kernel<<<256, 256, 0, stream>>>(enc, xbuf, flagp);

  // enc_proj (bf16 scratch): [12544,512] x We[512,512] + be
  gemm_bt<<<dim3(4, 98), 256, 0, stream>>>(enc, We, be, encp, 512, 512, flagp, 2, 2, 2, 0, 0);
  // embproj (fp32 scratch): [2048,512] x WiheP[2048,512] + (b_ih+b_hh)
  gemm_bt<<<dim3(16, 16), 256, 0, stream>>>(embA, WiheP, bias2, embp, 2048, 512, flagp, 0, 0, 1, 1, 0);

  // all 32 timesteps in one persistent kernel
  loop_kernel<<<64, 512, 0, stream>>>(encp, WdP, bd, vw, W2p, embp, enc, xbuf, hs, bar, flagp);

  // fc head: [2048,512] x Wf[32000,512] + bf -> d_out [B,T,V] (XCD-chunked swizzle)
  gemm_bt<<<dim3(250, 16), 256, 0, stream>>>(hs, Wf, bfv, d_out, 32000, 512, flagp, 0, 2, 2, 2, 1);
}

// Round 3
// 1644.990 us; speedup vs baseline: 2.1587x; 1.8219x over previous
//
#include <hip/hip_runtime.h>
#include <cstdint>
#include <cstddef>

// ---------------------------------------------------------------------------
// EnhancedRNN (attention LSTM captioner). B=64, L=196, FEAT=512, T=32,
// H=512, D=512, V=32000.
//
// Round 7: 4x parallelism in the persistent loop. Round-6 post-mortem: the
// loop is Little's-law latency-bound (64 blocks = 6% occupancy, 277 GB/s)
// and the per-XCD working set (5.9 MB) thrashes the 4 MB XCD-L2 every step
// (653 MB refetch). Now 256 blocks (1/CU, all co-resident):
//  - block (b = blk&63, q = blk>>6); siblings of a batch share an XCD.
//  - phase A: dec split by j-quarter (WdP slice 128 KB/block); partial
//    scores separable over j -> sys partials -> barrier -> replicated
//    softmax -> ctx split by f-quarter reading bf16 encB (footprint /2).
//  - phase B: block (bq=q, js=b) does 16 batches x 32 gates, K=1024 staged
//    in swizzled LDS, K-quartered across 8 waves, LDS-reduced; embp
//    prefetched to a register. c-state stays in registers.
//  - 3 grid barriers/step (93 total), fence-free sys-scope protocol.
// ---------------------------------------------------------------------------

typedef unsigned short u16;
typedef short  s16x8  __attribute__((ext_vector_type(8)));
typedef __bf16 bf16x8 __attribute__((ext_vector_type(8)));
typedef float  f32x4  __attribute__((ext_vector_type(4)));

__device__ __forceinline__ float bf2f(u16 u) {
  union { unsigned int i; float f; } x; x.i = ((unsigned int)u) << 16; return x.f;
}
__device__ __forceinline__ u16 f2bf(float f) {
  union { float f; unsigned int i; } x; x.f = f;
  unsigned int u = x.i;
  return (u16)((u + 0x7fffu + ((u >> 16) & 1u)) >> 16);   // RNE
}
__device__ __forceinline__ float fsig(float x) { return 1.f / (1.f + __expf(-x)); }
__device__ __forceinline__ float ftanh(float x) { float e = __expf(2.f * x); return 1.f - 2.f / (e + 1.f); }

__device__ __forceinline__ bf16x8 lds_frag(const u16* p) {
  s16x8 r = *(const s16x8*)p;
  return __builtin_bit_cast(bf16x8, r);
}

// flag-aware scalar load (input tensors may be fp32 or bf16)
__device__ __forceinline__ float ldf(const void* p, size_t idx, int f32) {
  return f32 ? ((const float*)p)[idx] : bf2f(((const u16*)p)[idx]);
}
// flag-aware 8-element load -> bf16 bits (for LDS staging)
__device__ __forceinline__ s16x8 ld8(const void* p, size_t idx, int f32) {
  if (f32) {
    f32x4 a = *(const f32x4*)((const float*)p + idx);
    f32x4 b = *(const f32x4*)((const float*)p + idx + 4);
    s16x8 r;
    r[0] = (short)f2bf(a[0]); r[1] = (short)f2bf(a[1]);
    r[2] = (short)f2bf(a[2]); r[3] = (short)f2bf(a[3]);
    r[4] = (short)f2bf(b[0]); r[5] = (short)f2bf(b[1]);
    r[6] = (short)f2bf(b[2]); r[7] = (short)f2bf(b[3]);
    return r;
  }
  return *(const s16x8*)((const u16*)p + idx);
}

// system-scope (coherence-point) accessors for cross-block data
__device__ __forceinline__ unsigned ld32_sys(const u16* p) {
  return __hip_atomic_load((const unsigned*)p, __ATOMIC_RELAXED, __HIP_MEMORY_SCOPE_SYSTEM);
}
__device__ __forceinline__ void st32_sys(u16* p, unsigned v) {
  __hip_atomic_store((unsigned*)p, v, __ATOMIC_RELAXED, __HIP_MEMORY_SCOPE_SYSTEM);
}
__device__ __forceinline__ s16x8 ld8_sys(const u16* p) {
  union { unsigned long long q[2]; s16x8 v; } x;
  x.q[0] = __hip_atomic_load((const unsigned long long*)p, __ATOMIC_RELAXED, __HIP_MEMORY_SCOPE_SYSTEM);
  x.q[1] = __hip_atomic_load((const unsigned long long*)(p + 4), __ATOMIC_RELAXED, __HIP_MEMORY_SCOPE_SYSTEM);
  return x.v;
}
__device__ __forceinline__ float ldf_sys(const float* p) {
  unsigned v = __hip_atomic_load((const unsigned*)p, __ATOMIC_RELAXED, __HIP_MEMORY_SCOPE_SYSTEM);
  union { unsigned u; float f; } x; x.u = v; return x.f;
}
__device__ __forceinline__ void stf_sys(float* p, float f) {
  union { float f; unsigned u; } x; x.f = f;
  __hip_atomic_store((unsigned*)p, x.u, __ATOMIC_RELAXED, __HIP_MEMORY_SCOPE_SYSTEM);
}

// ---------------------------------------------------------------------------
// Dtype detect (1 = fp32, 0 = bf16). Also zeroes the grid-barrier counter.
// ---------------------------------------------------------------------------
__global__ void detect_kernel(const unsigned int* __restrict__ w, int* __restrict__ flagp,
                              unsigned* __restrict__ barp) {
  __shared__ int votes[256];
  if (threadIdx.x == 0)
    __hip_atomic_store(barp, 0u, __ATOMIC_RELAXED, __HIP_MEMORY_SCOPE_SYSTEM);
  int v = 0;
#pragma unroll
  for (int i = 0; i < 4; ++i) {
    unsigned int x = w[threadIdx.x * 4 + i];
    int e = (x >> 7) & 0xFF;
    v += (e >= 100 && e <= 135) ? 1 : 0;
  }
  votes[threadIdx.x] = v;
  __syncthreads();
  for (int s = 128; s; s >>= 1) {
    if (threadIdx.x < s) votes[threadIdx.x] += votes[threadIdx.x + s];
    __syncthreads();
  }
  if (threadIdx.x == 0) flagp[0] = (votes[0] < 512) ? 1 : 0;
}

// ---------------------------------------------------------------------------
// bt-GEMM: C[m,n] = sum_k A[m,k]*B[n,k] + bias[n].
// swz=1: bijective XCD-chunked remap, m-fastest within XCD.
// ---------------------------------------------------------------------------
__global__ __launch_bounds__(256, 2) void gemm_bt(const void* __restrict__ A,
                                                  const void* __restrict__ Bm,
                                                  const void* __restrict__ bias,
                                                  void* __restrict__ Cout,
                                                  int N, int K,
                                                  const int* __restrict__ flagp,
                                                  int aMode, int bMode,
                                                  int biasMode, int outMode,
                                                  int swz) {
  const int fg = flagp ? flagp[0] : 0;
  const int af32 = (aMode == 1) || (aMode == 2 && fg);
  const int bf32 = (bMode == 1) || (bMode == 2 && fg);
  const int biasf32 = (biasMode == 1) || (biasMode == 2 && fg);
  const int of32 = (outMode == 1) || (outMode == 2 && fg);

  int bx = blockIdx.x, by = blockIdx.y;
  if (swz) {
    const int nx = gridDim.x, ny = gridDim.y;
    const int nwg = nx * ny;
    const int orig = by * nx + bx;
    const int q = nwg >> 3, r = nwg & 7;
    const int xcd = orig & 7, s = orig >> 3;
    const int wg = (xcd < r ? xcd * (q + 1) : r * (q + 1) + (xcd - r) * q) + s;
    by = wg % ny;          // m-fastest within each XCD's contiguous chunk
    bx = wg / ny;
  }

  __shared__ __align__(16) u16 As[128 * 64];
  __shared__ __align__(16) u16 Bs[128 * 64];
  const int tid = threadIdx.x;
  const int w = tid >> 6, lane = tid & 63;
  const int lm = lane & 15, quad = lane >> 4;
  const int tm0 = by * 128, tn0 = bx * 128;
  const int wm = (w >> 1) * 64, wn = (w & 1) * 64;
  const int srow = tid >> 3, schunk = tid & 7;   // 32 rows x 8 chunks per pass

  f32x4 acc[4][4] = {};

  for (int kt = 0; kt < K; kt += 64) {
    s16x8 ra[4], rb[4];
#pragma unroll
    for (int i = 0; i < 4; ++i) {
      int r = i * 32 + srow;
      ra[i] = ld8(A, (size_t)(tm0 + r) * K + kt + schunk * 8, af32);
      rb[i] = ld8(Bm, (size_t)(tn0 + r) * K + kt + schunk * 8, bf32);
    }
    __syncthreads();                      // prior iteration's LDS reads done
#pragma unroll
    for (int i = 0; i < 4; ++i) {
      int r = i * 32 + srow;
      *(s16x8*)(As + r * 64 + schunk * 8) = ra[i];
      *(s16x8*)(Bs + r * 64 + schunk * 8) = rb[i];
    }
    __syncthreads();
#pragma unroll
    for (int ks = 0; ks < 2; ++ks) {
      bf16x8 af[4], bfr[4];
#pragma unroll
      for (int mi = 0; mi < 4; ++mi)
        af[mi] = lds_frag(&As[(wm + mi * 16 + lm) * 64 + (ks * 4 + quad) * 8]);
#pragma unroll
      for (int ni = 0; ni < 4; ++ni)
        bfr[ni] = lds_frag(&Bs[(wn + ni * 16 + lm) * 64 + (ks * 4 + quad) * 8]);
#pragma unroll
      for (int mi = 0; mi < 4; ++mi)
#pragma unroll
        for (int ni = 0; ni < 4; ++ni)
          acc[mi][ni] = __builtin_amdgcn_mfma_f32_16x16x32_bf16(af[mi], bfr[ni], acc[mi][ni], 0, 0, 0);
    }
  }

#pragma unroll
  for (int mi = 0; mi < 4; ++mi)
#pragma unroll
    for (int ni = 0; ni < 4; ++ni) {
      int col = tn0 + wn + ni * 16 + lm;
      float bv = ldf(bias, col, biasf32);
#pragma unroll
      for (int r = 0; r < 4; ++r) {
        int row = tm0 + wm + mi * 16 + quad * 4 + r;   // C/D: col=lane&15, row=quad*4+reg
        float v = acc[mi][ni][r] + bv;
        if (of32) ((float*)Cout)[(size_t)row * N + col] = v;
        else      ((u16*)Cout)[(size_t)row * N + col] = f2bf(v);
      }
    }
}

// ---------------------------------------------------------------------------
// Pack/precompute: gate-interleaved weight packing, combined LSTM bias, emb
// gather, WdP (coalesced dec-proj layout), and encB = bf16 copy of enc.
// ---------------------------------------------------------------------------
__global__ void pack_kernel(const int* __restrict__ caps, const void* __restrict__ embed,
                            const void* __restrict__ Wih, const void* __restrict__ Whh,
                            const void* __restrict__ bih, const void* __restrict__ bhh,
                            const void* __restrict__ Wd, const void* __restrict__ enc,
                            u16* __restrict__ WiheP, u16* __restrict__ W2p,
                            float* __restrict__ bias2, u16* __restrict__ embA,
                            u16* __restrict__ WdP, u16* __restrict__ encB,
                            const int* __restrict__ flagp) {
  const int fg = flagp[0];
  const int total = 10881024;
  for (int idx = blockIdx.x * blockDim.x + threadIdx.x; idx < total; idx += gridDim.x * blockDim.x) {
    if (idx < 1048576) {                       // WiheP[2048][512] (emb half of W_ih)
      int jp = idx >> 9, kk = idx & 511;
      int j = (jp & 3) * 512 + (jp >> 2);      // jp = k*4+gate -> torch row j = gate*512+k
      WiheP[idx] = f2bf(ldf(Wih, (size_t)j * 1024 + kk, fg));
    } else if (idx < 3145728) {                // W2p[2048][1024] = [Wih_ctx | Whh]
      int q = idx - 1048576;
      int jp = q >> 10, kk = q & 1023;
      int j = (jp & 3) * 512 + (jp >> 2);
      float v = (kk < 512) ? ldf(Wih, (size_t)j * 1024 + 512 + kk, fg)
                           : ldf(Whh, (size_t)j * 512 + (kk - 512), fg);
      W2p[q] = f2bf(v);
    } else if (idx < 3147776) {                // bias2 (packed order)
      int jp = idx - 3145728;
      int j = (jp & 3) * 512 + (jp >> 2);
      bias2[jp] = ldf(bih, j, fg) + ldf(bhh, j, fg);
    } else if (idx < 4196352) {                // embA[2048][512], row m = b*32+t
      int q = idx - 3147776;
      int m = q >> 9, kk = q & 511;
      embA[q] = f2bf(ldf(embed, (size_t)caps[m] * 512 + kk, fg));
    } else if (idx < 4458496) {                // WdP[(k8*512+j)*8+jj] = Wd[j][k8*8+jj]
      int q = idx - 4196352;
      int jj = q & 7, j = (q >> 3) & 511, k8 = q >> 12;
      WdP[q] = f2bf(ldf(Wd, (size_t)j * 512 + k8 * 8 + jj, fg));
    } else {                                   // encB: bf16 copy of enc (linear)
      int q = idx - 4458496;
      encB[q] = f2bf(ldf(enc, (size_t)q, fg));
    }
  }
}

// init: ctx0 = mean_l(enc) into xcat0 ctx-half; h-half of xcat0 = 0.
__global__ void init_kernel(const void* __restrict__ enc, u16* __restrict__ xcat0,
                            const int* __restrict__ flagp) {
  const int fg = flagp[0];
  int i = blockIdx.x * blockDim.x + threadIdx.x;      // 65536 threads
  if (i < 32768) {
    int b = i >> 9, f = i & 511;
    size_t base = (size_t)b * 196 * 512 + f;
    float s = 0.f;
    for (int l = 0; l < 196; ++l) s += ldf(enc, base + (size_t)l * 512, fg);
    xcat0[b * 1024 + f] = f2bf(s * (1.f / 196.f));
  } else {
    int j = i - 32768;
    int b = j >> 9, k = j & 511;
    xcat0[b * 1024 + 512 + k] = 0;                    // bf16 +0
  }
}

// ---------------------------------------------------------------------------
// Persistent step loop: 256 blocks x 512 threads (1 block/CU, LDS 113 KB
// forces spread; all co-resident). Fence-free sys-scope grid barrier.
// ---------------------------------------------------------------------------
struct __align__(16) LoopSmem {
  union {
    struct {                       // phase A (~7.7 KB)
      float hb[512];
      float decp[4][128];
      float decs[128];
      float sc[200];
      float red[2];
      float ctxp[4][128];
      u16   ctxb[128];
    } a;
    struct {                       // phase B (~107 KB)
      u16   As[16 * 1024];         // 32 KB, row stride 2048 B, XOR-swizzled
      u16   Bs[32 * 1024];         // 64 KB
      float gf[8][16][17];         // per-wave partial tiles
      float gg[16][33];            // reduced gates
      u16   hbl[16][8];
    } b;
  } u;
  float vb[512];
  float bdv[512];
};

__device__ __forceinline__ void gsync(unsigned* bar, unsigned& ph) {
  __syncthreads();                 // drains vmcnt for all waves -> sys stores done
  if (threadIdx.x == 0) {
    ++ph;
    __hip_atomic_fetch_add(bar, 1u, __ATOMIC_RELAXED, __HIP_MEMORY_SCOPE_SYSTEM);
    const unsigned target = 256u * ph;
    while (__hip_atomic_load(bar, __ATOMIC_RELAXED, __HIP_MEMORY_SCOPE_SYSTEM) < target)
      __builtin_amdgcn_s_sleep(2);
  }
  __syncthreads();
}

// XOR swizzle for 2048-B-stride LDS rows (16 B granularity, rows mod 8)
__device__ __forceinline__ int swz2(int row, int colByte) {
  return row * 2048 + (colByte ^ ((row & 7) << 4));
}

__global__ __launch_bounds__(512) void loop_kernel(
    const u16* __restrict__ encp, const u16* __restrict__ WdP,
    const void* __restrict__ bd, const void* __restrict__ vw,
    const u16* __restrict__ W2p, const float* __restrict__ embp,
    const u16* __restrict__ encB, u16* xbuf, u16* __restrict__ hs,
    float* scp, unsigned* bar, const int* __restrict__ flagp) {
  __shared__ LoopSmem sm;
  const int fg = flagp[0];
  const int tid = threadIdx.x;
  const int blk = blockIdx.x;
  const int w = tid >> 6, lane = tid & 63;
  const int lm = lane & 15, quad = lane >> 4;
  const int bA = blk & 63, qA = blk >> 6;     // phase A: batch, quarter
  const int js = bA, bq = qA;                 // phase B: jp-slice, batch-quarter

  sm.vb[tid]  = ldf(vw, tid, fg);
  sm.bdv[tid] = ldf(bd, tid, fg);
  // c-state for (b = bq*16 + tid>>3, k = js*8 + (tid&7)), threads tid<128
  float c_reg = 0.f;
  unsigned ph = 0;

  for (int t = 0; t < 32; ++t) {
    u16* xin  = xbuf + (size_t)(t & 1) * 65536;        // [64][ctx|h] this step
    u16* hout = xbuf + (size_t)((t + 1) & 1) * 65536;  // h for next step

    if (t > 0) {
      // ============ phase A: attention for batch bA, quarter qA ============
      if (tid < 256) {                         // A1: h (sys, written last step)
        unsigned qv = ld32_sys(xin + bA * 1024 + 512 + 2 * tid);
        sm.u.a.hb[2 * tid]     = bf2f((u16)(qv & 0xffffu));
        sm.u.a.hb[2 * tid + 1] = bf2f((u16)(qv >> 16));
      }
      __syncthreads();
      { // A2: dec j-slice [qA*128, +128), K split 4-way across thread groups
        const int jl = tid & 127, kh = tid >> 7;
        float a = 0.f;
        const u16* wp = WdP + ((size_t)(kh * 16) * 512 + qA * 128 + jl) * 8;
#pragma unroll 4
        for (int k8 = 0; k8 < 16; ++k8) {
          s16x8 v = *(const s16x8*)(wp + (size_t)k8 * 4096);
#pragma unroll
          for (int j = 0; j < 8; ++j) a += bf2f((u16)v[j]) * sm.u.a.hb[(kh * 16 + k8) * 8 + j];
        }
        sm.u.a.decp[kh][jl] = a;
      }
      __syncthreads();
      if (tid < 128)
        sm.u.a.decs[tid] = sm.bdv[qA * 128 + tid] +
            ((sm.u.a.decp[0][tid] + sm.u.a.decp[1][tid]) +
             (sm.u.a.decp[2][tid] + sm.u.a.decp[3][tid]));
      __syncthreads();
      { // A3: partial scores over j-slice for all l (separable over j)
        const int lsub = lane >> 4, jc = lane & 15;
        float dv[8], vv[8];
#pragma unroll
        for (int j = 0; j < 8; ++j) {
          dv[j] = sm.u.a.decs[jc * 8 + j];
          vv[j] = sm.vb[qA * 128 + jc * 8 + j];
        }
        for (int l0 = w * 4; l0 < 196; l0 += 32) {
          const int l = l0 + lsub;
          s16x8 ev = *(const s16x8*)(encp + ((size_t)(bA * 196 + l)) * 512 + qA * 128 + jc * 8);
          float s = 0.f;
#pragma unroll
          for (int j = 0; j < 8; ++j) s += vv[j] * ftanh(bf2f((u16)ev[j]) + dv[j]);
          s += __shfl_xor(s, 1, 64); s += __shfl_xor(s, 2, 64);
          s += __shfl_xor(s, 4, 64); s += __shfl_xor(s, 8, 64);
          if (jc == 0) stf_sys(scp + ((size_t)(bA * 4 + qA)) * 256 + l, s);
        }
      }
      gsync(bar, ph);   // barrier 1: score partials visible
      // A4: sum partials + softmax (replicated across the 4 siblings)
      if (tid < 196) {
        float s = (ldf_sys(scp + (size_t)(bA * 4 + 0) * 256 + tid) +
                   ldf_sys(scp + (size_t)(bA * 4 + 1) * 256 + tid)) +
                  (ldf_sys(scp + (size_t)(bA * 4 + 2) * 256 + tid) +
                   ldf_sys(scp + (size_t)(bA * 4 + 3) * 256 + tid));
        sm.u.a.sc[tid] = s;
      }
      __syncthreads();
      if (tid < 64) {
        float m = -1e30f;
        for (int l = tid; l < 196; l += 64) m = fmaxf(m, sm.u.a.sc[l]);
#pragma unroll
        for (int o = 32; o; o >>= 1) m = fmaxf(m, __shfl_xor(m, o, 64));
        if (tid == 0) sm.u.a.red[0] = m;
      }
      __syncthreads();
      if (tid < 196) sm.u.a.sc[tid] = __expf(sm.u.a.sc[tid] - sm.u.a.red[0]);
      __syncthreads();
      if (tid < 64) {
        float s = 0.f;
        for (int l = tid; l < 196; l += 64) s += sm.u.a.sc[l];
#pragma unroll
        for (int o = 32; o; o >>= 1) s += __shfl_xor(s, o, 64);
        if (tid == 0) sm.u.a.red[1] = 1.f / s;
      }
      __syncthreads();
      { // A5: ctx f-slice [qA*128, +128): l split 4-way, bf16 encB reads
        const int lgrp = tid >> 7, fl = tid & 127;
        const u16* eb = encB + ((size_t)bA * 196) * 512 + qA * 128 + fl;
        float a = 0.f;
#pragma unroll 7
        for (int i = 0; i < 49; ++i) {
          const int l = lgrp * 49 + i;
          a += sm.u.a.sc[l] * bf2f(eb[(size_t)l * 512]);
        }
        sm.u.a.ctxp[lgrp][fl] = a;
      }
      __syncthreads();
      if (tid < 128) {
        float v2 = ((sm.u.a.ctxp[0][tid] + sm.u.a.ctxp[1][tid]) +
                    (sm.u.a.ctxp[2][tid] + sm.u.a.ctxp[3][tid])) * sm.u.a.red[1];
        sm.u.a.ctxb[tid] = f2bf(v2);
      }
      __syncthreads();
      if (tid < 64) {
        unsigned pv = (unsigned)sm.u.a.ctxb[2 * tid] | ((unsigned)sm.u.a.ctxb[2 * tid + 1] << 16);
        st32_sys(xin + bA * 1024 + qA * 128 + 2 * tid, pv);
      }
      gsync(bar, ph);   // barrier 2: ctx visible before gates
    }

    // ============ phase B: gates for batches [bq*16,+16), jp [js*32,+32) ============
    // embp prefetch (register) -- hides cold-HBM latency under staging+MFMA
    float epv;
    {
      const int bl = tid >> 5, jl = tid & 31;
      epv = embp[((size_t)((bq * 16 + bl) * 32 + t)) * 2048 + js * 32 + jl];
    }
    // stage A (xin rows, sys) and B (W2p rows) into swizzled LDS
#pragma unroll
    for (int i = 0; i < 4; ++i) {
      const int c = tid + i * 512;              // 16 rows x 128 chunks
      const int row = c >> 7, col8 = c & 127;
      s16x8 v = ld8_sys(xin + (size_t)(bq * 16 + row) * 1024 + col8 * 8);
      *(s16x8*)((char*)sm.u.b.As + swz2(row, col8 * 16)) = v;
    }
#pragma unroll
    for (int i = 0; i < 8; ++i) {
      const int c = tid + i * 512;              // 32 rows x 128 chunks
      const int row = c >> 7, col8 = c & 127;
      s16x8 v = *(const s16x8*)(W2p + (size_t)(js * 32 + row) * 1024 + col8 * 8);
      *(s16x8*)((char*)sm.u.b.Bs + swz2(row, col8 * 16)) = v;
    }
    __syncthreads();
    { // MFMA: wave w = (kq = w>>1 K-quarter, ni = w&1 n-tile); 8 mfma each
      const int kq = w >> 1, ni = w & 1;
      f32x4 acc = {};
#pragma unroll
      for (int kk = 0; kk < 8; ++kk) {
        const int kcolB = (kq * 256 + kk * 32 + quad * 8) * 2;
        bf16x8 af = lds_frag((const u16*)((const char*)sm.u.b.As + swz2(lm, kcolB)));
        bf16x8 bf = lds_frag((const u16*)((const char*)sm.u.b.Bs + swz2(ni * 16 + lm, kcolB)));
        acc = __builtin_amdgcn_mfma_f32_16x16x32_bf16(af, bf, acc, 0, 0, 0);
      }
#pragma unroll
      for (int r = 0; r < 4; ++r)               // C/D: col=lane&15, row=quad*4+reg
        sm.u.b.gf[w][quad * 4 + r][lm] = acc[r];
    }
    __syncthreads();
    { // reduce K-quarters + embp
      const int bl = tid >> 5, jl = tid & 31;
      const int nn = jl >> 4, cc = jl & 15;
      float g = ((sm.u.b.gf[nn][bl][cc] + sm.u.b.gf[2 + nn][bl][cc]) +
                 (sm.u.b.gf[4 + nn][bl][cc] + sm.u.b.gf[6 + nn][bl][cc])) + epv;
      sm.u.b.gg[bl][jl] = g;
    }
    __syncthreads();
    if (tid < 128) {   // LSTM pointwise; c in register
      const int bl = tid >> 3, kl = tid & 7;
      const float gi = sm.u.b.gg[bl][kl * 4 + 0];
      const float gf_ = sm.u.b.gg[bl][kl * 4 + 1];
      const float ggv = sm.u.b.gg[bl][kl * 4 + 2];
      const float go = sm.u.b.gg[bl][kl * 4 + 3];
      c_reg = fsig(gf_) * c_reg + fsig(gi) * ftanh(ggv);
      const float h2 = fsig(go) * ftanh(c_reg);
      const u16 hb2 = f2bf(h2);
      const int bg = bq * 16 + bl, kg = js * 8 + kl;
      hs[(size_t)(bg * 32 + t) * 512 + kg] = hb2;   // normal store (post-kernel use)
      sm.u.b.hbl[bl][kl] = hb2;
    }
    __syncthreads();
    if (tid < 64) {    // pack h pairs -> sys store
      const int bl = tid >> 2, p = tid & 3;
      unsigned pv = (unsigned)sm.u.b.hbl[bl][2 * p] | ((unsigned)sm.u.b.hbl[bl][2 * p + 1] << 16);
      st32_sys(hout + (size_t)(bq * 16 + bl) * 1024 + 512 + js * 8 + 2 * p, pv);
    }
    if (t < 31) gsync(bar, ph);   // barrier 3: h visible for next attention
  }
}

// ---------------------------------------------------------------------------
// Scratch layout inside d_out (262 MB; all dead before the final fc GEMM):
// ---------------------------------------------------------------------------
static constexpr size_t OFF_ENCP = 0;                       // u16 [12544][512]
static constexpr size_t OFF_EMBP = 16777216;                // f32 [2048][2048]
static constexpr size_t OFF_EMBA = 33554432;                // u16 [2048][512]
static constexpr size_t OFF_WIHE = 35651584;                // u16 [2048][512]
static constexpr size_t OFF_W2P  = 37748736;                // u16 [2048][1024]
static constexpr size_t OFF_B2   = 41943040;                // f32 [2048]
static constexpr size_t OFF_XC0  = 41951232;                // u16 [2][64][1024]
static constexpr size_t OFF_WDP  = 42213376;                // u16 [64][512][8]
static constexpr size_t OFF_BAR  = 42737664;                // u32 barrier counter
static constexpr size_t OFF_SCP  = 42737792;                // f32 [64][4][256] partials
static constexpr size_t OFF_ENCB = 42999936;                // u16 [64][196][512]
// d_ws: hs (u16 [2048][512] = 2 MB) + dtype flag (int).

extern "C" void kernel_launch(void* const* d_in, const int* in_sizes, int n_in,
                              void* d_out, int out_size, void* d_ws, size_t ws_size,
                              hipStream_t stream) {
  const void* enc   = d_in[0];
  const int*  caps  = (const int*)d_in[1];
  const void* embed = d_in[2];
  const void* We    = d_in[3];
  const void* be    = d_in[4];
  const void* Wd    = d_in[5];
  const void* bd    = d_in[6];
  const void* vw    = d_in[7];
  // d_in[8] (v_b) unused: constant shift inside softmax
  const void* Wih   = d_in[9];
  const void* Whh   = d_in[10];
  const void* bih   = d_in[11];
  const void* bhh   = d_in[12];
  const void* Wf    = d_in[13];
  const void* bfv   = d_in[14];

  char* ob = (char*)d_out;
  u16*      encp   = (u16*)(ob + OFF_ENCP);
  float*    embp   = (float*)(ob + OFF_EMBP);
  u16*      embA   = (u16*)(ob + OFF_EMBA);
  u16*      WiheP  = (u16*)(ob + OFF_WIHE);
  u16*      W2p    = (u16*)(ob + OFF_W2P);
  float*    bias2  = (float*)(ob + OFF_B2);
  u16*      xbuf   = (u16*)(ob + OFF_XC0);
  u16*      WdP    = (u16*)(ob + OFF_WDP);
  unsigned* bar    = (unsigned*)(ob + OFF_BAR);
  float*    scp    = (float*)(ob + OFF_SCP);
  u16*      encB   = (u16*)(ob + OFF_ENCB);
  u16*      hs     = (u16*)d_ws;
  int*      flagp  = (int*)((char*)d_ws + 2048ull * 512 * 2);

  detect_kernel<<<1, 256, 0, stream>>>((const unsigned int*)embed, flagp, bar);
  pack_kernel<<<4096, 256, 0, stream>>>(caps, embed, Wih, Whh, bih, bhh, Wd, enc,
                                        WiheP, W2p, bias2, embA, WdP, encB, flagp);
  init_kernel<<<256, 256, 0, stream>>>(enc, xbuf, flagp);

  // enc_proj (bf16 scratch): [12544,512] x We[512,512] + be
  gemm_bt<<<dim3(4, 98), 256, 0, stream>>>(enc, We, be, encp, 512, 512, flagp, 2, 2, 2, 0, 0);
  // embproj (fp32 scratch): [2048,512] x WiheP[2048,512] + (b_ih+b_hh)
  gemm_bt<<<dim3(16, 16), 256, 0, stream>>>(embA, WiheP, bias2, embp, 2048, 512, flagp, 0, 0, 1, 1, 0);

  // all 32 timesteps in one persistent kernel, 256 blocks (1/CU)
  loop_kernel<<<256, 512, 0, stream>>>(encp, WdP, bd, vw, W2p, embp, encB,
                                       xbuf, hs, scp, bar, flagp);

  // fc head: [2048,512] x Wf[32000,512] + bf -> d_out [B,T,V] (XCD swizzle)
  gemm_bt<<<dim3(250, 16), 256, 0, stream>>>(hs, Wf, bfv, d_out, 32000, 512, flagp, 0, 2, 2, 2, 1);
}

// Round 4
// 1297.558 us; speedup vs baseline: 2.7368x; 1.2678x over previous
//
#include <hip/hip_runtime.h>
#include <cstdint>
#include <cstddef>

// ---------------------------------------------------------------------------
// EnhancedRNN (attention LSTM captioner). B=64, L=196, FEAT=512, T=32,
// H=512, D=512, V=32000.
//
// Round 8: flag-based producer/consumer sync replaces the 3 global grid
// barriers per step. Round-7 post-mortem: 93 global barriers, each 256
// same-address sys atomicAdds (serialized at the L3 bank) + full-grid
// convoy = the dominant per-step cost (31.6 us/step vs ~8 us of work).
// Dependencies are local: scores = 4 sibling blocks; ctx/h = 64-block
// producer sets. Each producer sets a per-block flag (value = step, sys
// store, fully parallel); consumers poll <=64 flags with one coalesced
// wave-load + __all. Skew pipelines instead of convoying. W2p staging +
// embp prefetch hoisted before the phase-B waits. Math bit-identical.
// ---------------------------------------------------------------------------

typedef unsigned short u16;
typedef short  s16x8  __attribute__((ext_vector_type(8)));
typedef __bf16 bf16x8 __attribute__((ext_vector_type(8)));
typedef float  f32x4  __attribute__((ext_vector_type(4)));

__device__ __forceinline__ float bf2f(u16 u) {
  union { unsigned int i; float f; } x; x.i = ((unsigned int)u) << 16; return x.f;
}
__device__ __forceinline__ u16 f2bf(float f) {
  union { float f; unsigned int i; } x; x.f = f;
  unsigned int u = x.i;
  return (u16)((u + 0x7fffu + ((u >> 16) & 1u)) >> 16);   // RNE
}
__device__ __forceinline__ float fsig(float x) { return 1.f / (1.f + __expf(-x)); }
__device__ __forceinline__ float ftanh(float x) { float e = __expf(2.f * x); return 1.f - 2.f / (e + 1.f); }

__device__ __forceinline__ bf16x8 lds_frag(const u16* p) {
  s16x8 r = *(const s16x8*)p;
  return __builtin_bit_cast(bf16x8, r);
}

// flag-aware scalar load (input tensors may be fp32 or bf16)
__device__ __forceinline__ float ldf(const void* p, size_t idx, int f32) {
  return f32 ? ((const float*)p)[idx] : bf2f(((const u16*)p)[idx]);
}
// flag-aware 8-element load -> bf16 bits (for LDS staging)
__device__ __forceinline__ s16x8 ld8(const void* p, size_t idx, int f32) {
  if (f32) {
    f32x4 a = *(const f32x4*)((const float*)p + idx);
    f32x4 b = *(const f32x4*)((const float*)p + idx + 4);
    s16x8 r;
    r[0] = (short)f2bf(a[0]); r[1] = (short)f2bf(a[1]);
    r[2] = (short)f2bf(a[2]); r[3] = (short)f2bf(a[3]);
    r[4] = (short)f2bf(b[0]); r[5] = (short)f2bf(b[1]);
    r[6] = (short)f2bf(b[2]); r[7] = (short)f2bf(b[3]);
    return r;
  }
  return *(const s16x8*)((const u16*)p + idx);
}

// system-scope (coherence-point) accessors for cross-block data
__device__ __forceinline__ unsigned ldu_sys(const unsigned* p) {
  return __hip_atomic_load(p, __ATOMIC_RELAXED, __HIP_MEMORY_SCOPE_SYSTEM);
}
__device__ __forceinline__ void stu_sys(unsigned* p, unsigned v) {
  __hip_atomic_store(p, v, __ATOMIC_RELAXED, __HIP_MEMORY_SCOPE_SYSTEM);
}
__device__ __forceinline__ unsigned ld32_sys(const u16* p) {
  return __hip_atomic_load((const unsigned*)p, __ATOMIC_RELAXED, __HIP_MEMORY_SCOPE_SYSTEM);
}
__device__ __forceinline__ void st32_sys(u16* p, unsigned v) {
  __hip_atomic_store((unsigned*)p, v, __ATOMIC_RELAXED, __HIP_MEMORY_SCOPE_SYSTEM);
}
__device__ __forceinline__ s16x8 ld8_sys(const u16* p) {
  union { unsigned long long q[2]; s16x8 v; } x;
  x.q[0] = __hip_atomic_load((const unsigned long long*)p, __ATOMIC_RELAXED, __HIP_MEMORY_SCOPE_SYSTEM);
  x.q[1] = __hip_atomic_load((const unsigned long long*)(p + 4), __ATOMIC_RELAXED, __HIP_MEMORY_SCOPE_SYSTEM);
  return x.v;
}
__device__ __forceinline__ float ldf_sys(const float* p) {
  unsigned v = __hip_atomic_load((const unsigned*)p, __ATOMIC_RELAXED, __HIP_MEMORY_SCOPE_SYSTEM);
  union { unsigned u; float f; } x; x.u = v; return x.f;
}
__device__ __forceinline__ void stf_sys(float* p, float f) {
  union { float f; unsigned u; } x; x.f = f;
  __hip_atomic_store((unsigned*)p, x.u, __ATOMIC_RELAXED, __HIP_MEMORY_SCOPE_SYSTEM);
}

// one wave polls 64 consecutive flags (call under a single-wave guard;
// follow with __syncthreads())
__device__ __forceinline__ void poll64(const unsigned* f, unsigned target) {
  const int lane = threadIdx.x & 63;
  for (;;) {
    unsigned v = ldu_sys(f + lane);
    if (__all(v >= target)) break;
    __builtin_amdgcn_s_sleep(1);
  }
}

// ---------------------------------------------------------------------------
// Dtype detect (1 = fp32, 0 = bf16). Also zeroes the 3x256 sync flags.
// ---------------------------------------------------------------------------
__global__ void detect_kernel(const unsigned int* __restrict__ w, int* __restrict__ flagp,
                              unsigned* __restrict__ flags) {
  __shared__ int votes[256];
  stu_sys(flags + threadIdx.x, 0u);
  stu_sys(flags + 256 + threadIdx.x, 0u);
  stu_sys(flags + 512 + threadIdx.x, 0u);
  int v = 0;
#pragma unroll
  for (int i = 0; i < 4; ++i) {
    unsigned int x = w[threadIdx.x * 4 + i];
    int e = (x >> 7) & 0xFF;
    v += (e >= 100 && e <= 135) ? 1 : 0;
  }
  votes[threadIdx.x] = v;
  __syncthreads();
  for (int s = 128; s; s >>= 1) {
    if (threadIdx.x < s) votes[threadIdx.x] += votes[threadIdx.x + s];
    __syncthreads();
  }
  if (threadIdx.x == 0) flagp[0] = (votes[0] < 512) ? 1 : 0;
}

// ---------------------------------------------------------------------------
// bt-GEMM: C[m,n] = sum_k A[m,k]*B[n,k] + bias[n].
// swz=1: bijective XCD-chunked remap, m-fastest within XCD.
// ---------------------------------------------------------------------------
__global__ __launch_bounds__(256, 2) void gemm_bt(const void* __restrict__ A,
                                                  const void* __restrict__ Bm,
                                                  const void* __restrict__ bias,
                                                  void* __restrict__ Cout,
                                                  int N, int K,
                                                  const int* __restrict__ flagp,
                                                  int aMode, int bMode,
                                                  int biasMode, int outMode,
                                                  int swz) {
  const int fg = flagp ? flagp[0] : 0;
  const int af32 = (aMode == 1) || (aMode == 2 && fg);
  const int bf32 = (bMode == 1) || (bMode == 2 && fg);
  const int biasf32 = (biasMode == 1) || (biasMode == 2 && fg);
  const int of32 = (outMode == 1) || (outMode == 2 && fg);

  int bx = blockIdx.x, by = blockIdx.y;
  if (swz) {
    const int nx = gridDim.x, ny = gridDim.y;
    const int nwg = nx * ny;
    const int orig = by * nx + bx;
    const int q = nwg >> 3, r = nwg & 7;
    const int xcd = orig & 7, s = orig >> 3;
    const int wg = (xcd < r ? xcd * (q + 1) : r * (q + 1) + (xcd - r) * q) + s;
    by = wg % ny;          // m-fastest within each XCD's contiguous chunk
    bx = wg / ny;
  }

  __shared__ __align__(16) u16 As[128 * 64];
  __shared__ __align__(16) u16 Bs[128 * 64];
  const int tid = threadIdx.x;
  const int w = tid >> 6, lane = tid & 63;
  const int lm = lane & 15, quad = lane >> 4;
  const int tm0 = by * 128, tn0 = bx * 128;
  const int wm = (w >> 1) * 64, wn = (w & 1) * 64;
  const int srow = tid >> 3, schunk = tid & 7;   // 32 rows x 8 chunks per pass

  f32x4 acc[4][4] = {};

  for (int kt = 0; kt < K; kt += 64) {
    s16x8 ra[4], rb[4];
#pragma unroll
    for (int i = 0; i < 4; ++i) {
      int r = i * 32 + srow;
      ra[i] = ld8(A, (size_t)(tm0 + r) * K + kt + schunk * 8, af32);
      rb[i] = ld8(Bm, (size_t)(tn0 + r) * K + kt + schunk * 8, bf32);
    }
    __syncthreads();                      // prior iteration's LDS reads done
#pragma unroll
    for (int i = 0; i < 4; ++i) {
      int r = i * 32 + srow;
      *(s16x8*)(As + r * 64 + schunk * 8) = ra[i];
      *(s16x8*)(Bs + r * 64 + schunk * 8) = rb[i];
    }
    __syncthreads();
#pragma unroll
    for (int ks = 0; ks < 2; ++ks) {
      bf16x8 af[4], bfr[4];
#pragma unroll
      for (int mi = 0; mi < 4; ++mi)
        af[mi] = lds_frag(&As[(wm + mi * 16 + lm) * 64 + (ks * 4 + quad) * 8]);
#pragma unroll
      for (int ni = 0; ni < 4; ++ni)
        bfr[ni] = lds_frag(&Bs[(wn + ni * 16 + lm) * 64 + (ks * 4 + quad) * 8]);
#pragma unroll
      for (int mi = 0; mi < 4; ++mi)
#pragma unroll
        for (int ni = 0; ni < 4; ++ni)
          acc[mi][ni] = __builtin_amdgcn_mfma_f32_16x16x32_bf16(af[mi], bfr[ni], acc[mi][ni], 0, 0, 0);
    }
  }

#pragma unroll
  for (int mi = 0; mi < 4; ++mi)
#pragma unroll
    for (int ni = 0; ni < 4; ++ni) {
      int col = tn0 + wn + ni * 16 + lm;
      float bv = ldf(bias, col, biasf32);
#pragma unroll
      for (int r = 0; r < 4; ++r) {
        int row = tm0 + wm + mi * 16 + quad * 4 + r;   // C/D: col=lane&15, row=quad*4+reg
        float v = acc[mi][ni][r] + bv;
        if (of32) ((float*)Cout)[(size_t)row * N + col] = v;
        else      ((u16*)Cout)[(size_t)row * N + col] = f2bf(v);
      }
    }
}

// ---------------------------------------------------------------------------
// Pack/precompute: gate-interleaved weight packing, combined LSTM bias, emb
// gather, WdP (coalesced dec-proj layout), and encB = bf16 copy of enc.
// ---------------------------------------------------------------------------
__global__ void pack_kernel(const int* __restrict__ caps, const void* __restrict__ embed,
                            const void* __restrict__ Wih, const void* __restrict__ Whh,
                            const void* __restrict__ bih, const void* __restrict__ bhh,
                            const void* __restrict__ Wd, const void* __restrict__ enc,
                            u16* __restrict__ WiheP, u16* __restrict__ W2p,
                            float* __restrict__ bias2, u16* __restrict__ embA,
                            u16* __restrict__ WdP, u16* __restrict__ encB,
                            const int* __restrict__ flagp) {
  const int fg = flagp[0];
  const int total = 10881024;
  for (int idx = blockIdx.x * blockDim.x + threadIdx.x; idx < total; idx += gridDim.x * blockDim.x) {
    if (idx < 1048576) {                       // WiheP[2048][512] (emb half of W_ih)
      int jp = idx >> 9, kk = idx & 511;
      int j = (jp & 3) * 512 + (jp >> 2);      // jp = k*4+gate -> torch row j = gate*512+k
      WiheP[idx] = f2bf(ldf(Wih, (size_t)j * 1024 + kk, fg));
    } else if (idx < 3145728) {                // W2p[2048][1024] = [Wih_ctx | Whh]
      int q = idx - 1048576;
      int jp = q >> 10, kk = q & 1023;
      int j = (jp & 3) * 512 + (jp >> 2);
      float v = (kk < 512) ? ldf(Wih, (size_t)j * 1024 + 512 + kk, fg)
                           : ldf(Whh, (size_t)j * 512 + (kk - 512), fg);
      W2p[q] = f2bf(v);
    } else if (idx < 3147776) {                // bias2 (packed order)
      int jp = idx - 3145728;
      int j = (jp & 3) * 512 + (jp >> 2);
      bias2[jp] = ldf(bih, j, fg) + ldf(bhh, j, fg);
    } else if (idx < 4196352) {                // embA[2048][512], row m = b*32+t
      int q = idx - 3147776;
      int m = q >> 9, kk = q & 511;
      embA[q] = f2bf(ldf(embed, (size_t)caps[m] * 512 + kk, fg));
    } else if (idx < 4458496) {                // WdP[(k8*512+j)*8+jj] = Wd[j][k8*8+jj]
      int q = idx - 4196352;
      int jj = q & 7, j = (q >> 3) & 511, k8 = q >> 12;
      WdP[q] = f2bf(ldf(Wd, (size_t)j * 512 + k8 * 8 + jj, fg));
    } else {                                   // encB: bf16 copy of enc (linear)
      int q = idx - 4458496;
      encB[q] = f2bf(ldf(enc, (size_t)q, fg));
    }
  }
}

// init: ctx0 = mean_l(enc) into xcat0 ctx-half; h-half of xcat0 = 0.
__global__ void init_kernel(const void* __restrict__ enc, u16* __restrict__ xcat0,
                            const int* __restrict__ flagp) {
  const int fg = flagp[0];
  int i = blockIdx.x * blockDim.x + threadIdx.x;      // 65536 threads
  if (i < 32768) {
    int b = i >> 9, f = i & 511;
    size_t base = (size_t)b * 196 * 512 + f;
    float s = 0.f;
    for (int l = 0; l < 196; ++l) s += ldf(enc, base + (size_t)l * 512, fg);
    xcat0[b * 1024 + f] = f2bf(s * (1.f / 196.f));
  } else {
    int j = i - 32768;
    int b = j >> 9, k = j & 511;
    xcat0[b * 1024 + 512 + k] = 0;                    // bf16 +0
  }
}

// ---------------------------------------------------------------------------
// Persistent step loop: 256 blocks x 512 threads (1 block/CU). All sync is
// flag-based producer->consumer (sys-scope, parallel stores, coalesced
// wave polls). Flags monotone (value = step+1); no global barrier at all.
//   scF[bA*4+qA]  : score j-partials ready     (consumers: 4 siblings)
//   ctxF[bA*4+qA] : ctx f-slice ready          (consumers: 64 blocks, bq=bA>>4)
//   hF[blk]       : h slice ready (bq*64+js)   (consumers: 64 blocks)
// ---------------------------------------------------------------------------
struct __align__(16) LoopSmem {
  union {
    struct {                       // phase A (~7.7 KB)
      float hb[512];
      float decp[4][128];
      float decs[128];
      float sc[200];
      float red[2];
      float ctxp[4][128];
      u16   ctxb[128];
    } a;
    struct {                       // phase B (~107 KB)
      u16   As[16 * 1024];         // 32 KB, row stride 2048 B, XOR-swizzled
      u16   Bs[32 * 1024];         // 64 KB
      float gf[8][16][17];         // per-wave partial tiles
      float gg[16][33];            // reduced gates
      u16   hbl[16][8];
    } b;
  } u;
  float vb[512];
  float bdv[512];
};

// XOR swizzle for 2048-B-stride LDS rows (16 B granularity, rows mod 8)
__device__ __forceinline__ int swz2(int row, int colByte) {
  return row * 2048 + (colByte ^ ((row & 7) << 4));
}

__global__ __launch_bounds__(512) void loop_kernel(
    const u16* __restrict__ encp, const u16* __restrict__ WdP,
    const void* __restrict__ bd, const void* __restrict__ vw,
    const u16* __restrict__ W2p, const float* __restrict__ embp,
    const u16* __restrict__ encB, u16* xbuf, u16* __restrict__ hs,
    float* scp, unsigned* flags, const int* __restrict__ flagp) {
  __shared__ LoopSmem sm;
  const int fg = flagp[0];
  const int tid = threadIdx.x;
  const int blk = blockIdx.x;
  const int w = tid >> 6, lane = tid & 63;
  const int lm = lane & 15, quad = lane >> 4;
  const int bA = blk & 63, qA = blk >> 6;     // phase A: batch, quarter
  const int js = bA, bq = qA;                 // phase B: jp-slice, batch-quarter

  unsigned* scF  = flags;
  unsigned* ctxF = flags + 256;
  unsigned* hF   = flags + 512;

  sm.vb[tid]  = ldf(vw, tid, fg);
  sm.bdv[tid] = ldf(bd, tid, fg);
  // c-state for (b = bq*16 + tid>>3, k = js*8 + (tid&7)), threads tid<128
  float c_reg = 0.f;

  for (int t = 0; t < 32; ++t) {
    u16* xin  = xbuf + (size_t)(t & 1) * 65536;        // [64][ctx|h] this step
    u16* hout = xbuf + (size_t)((t + 1) & 1) * 65536;  // h for next step

    if (t > 0) {
      // ============ phase A: attention for batch bA, quarter qA ============
      if (tid < 64) poll64(hF + (bA >> 4) * 64, (unsigned)t);   // h(t) ready
      __syncthreads();
      if (tid < 256) {                         // A1: h (sys, written last step)
        unsigned qv = ld32_sys(xin + bA * 1024 + 512 + 2 * tid);
        sm.u.a.hb[2 * tid]     = bf2f((u16)(qv & 0xffffu));
        sm.u.a.hb[2 * tid + 1] = bf2f((u16)(qv >> 16));
      }
      __syncthreads();
      { // A2: dec j-slice [qA*128, +128), K split 4-way across thread groups
        const int jl = tid & 127, kh = tid >> 7;
        float a = 0.f;
        const u16* wp = WdP + ((size_t)(kh * 16) * 512 + qA * 128 + jl) * 8;
#pragma unroll 4
        for (int k8 = 0; k8 < 16; ++k8) {
          s16x8 v = *(const s16x8*)(wp + (size_t)k8 * 4096);
#pragma unroll
          for (int j = 0; j < 8; ++j) a += bf2f((u16)v[j]) * sm.u.a.hb[(kh * 16 + k8) * 8 + j];
        }
        sm.u.a.decp[kh][jl] = a;
      }
      __syncthreads();
      if (tid < 128)
        sm.u.a.decs[tid] = sm.bdv[qA * 128 + tid] +
            ((sm.u.a.decp[0][tid] + sm.u.a.decp[1][tid]) +
             (sm.u.a.decp[2][tid] + sm.u.a.decp[3][tid]));
      __syncthreads();
      { // A3: partial scores over j-slice for all l (separable over j)
        const int lsub = lane >> 4, jc = lane & 15;
        float dv[8], vv[8];
#pragma unroll
        for (int j = 0; j < 8; ++j) {
          dv[j] = sm.u.a.decs[jc * 8 + j];
          vv[j] = sm.vb[qA * 128 + jc * 8 + j];
        }
        for (int l0 = w * 4; l0 < 196; l0 += 32) {
          const int l = l0 + lsub;
          s16x8 ev = *(const s16x8*)(encp + ((size_t)(bA * 196 + l)) * 512 + qA * 128 + jc * 8);
          float s = 0.f;
#pragma unroll
          for (int j = 0; j < 8; ++j) s += vv[j] * ftanh(bf2f((u16)ev[j]) + dv[j]);
          s += __shfl_xor(s, 1, 64); s += __shfl_xor(s, 2, 64);
          s += __shfl_xor(s, 4, 64); s += __shfl_xor(s, 8, 64);
          if (jc == 0) stf_sys(scp + ((size_t)(bA * 4 + qA)) * 256 + l, s);
        }
      }
      __syncthreads();                         // partial stores drained
      if (tid == 0) stu_sys(scF + bA * 4 + qA, (unsigned)(t + 1));
      if (tid < 64) {                          // wait the 4 siblings' partials
        for (;;) {
          unsigned v = (tid < 4) ? ldu_sys(scF + bA * 4 + tid) : 0xffffffffu;
          if (__all(v >= (unsigned)(t + 1))) break;
          __builtin_amdgcn_s_sleep(1);
        }
      }
      __syncthreads();
      // A4: sum partials + softmax (replicated across the 4 siblings)
      if (tid < 196) {
        float s = (ldf_sys(scp + (size_t)(bA * 4 + 0) * 256 + tid) +
                   ldf_sys(scp + (size_t)(bA * 4 + 1) * 256 + tid)) +
                  (ldf_sys(scp + (size_t)(bA * 4 + 2) * 256 + tid) +
                   ldf_sys(scp + (size_t)(bA * 4 + 3) * 256 + tid));
        sm.u.a.sc[tid] = s;
      }
      __syncthreads();
      if (tid < 64) {
        float m = -1e30f;
        for (int l = tid; l < 196; l += 64) m = fmaxf(m, sm.u.a.sc[l]);
#pragma unroll
        for (int o = 32; o; o >>= 1) m = fmaxf(m, __shfl_xor(m, o, 64));
        if (tid == 0) sm.u.a.red[0] = m;
      }
      __syncthreads();
      if (tid < 196) sm.u.a.sc[tid] = __expf(sm.u.a.sc[tid] - sm.u.a.red[0]);
      __syncthreads();
      if (tid < 64) {
        float s = 0.f;
        for (int l = tid; l < 196; l += 64) s += sm.u.a.sc[l];
#pragma unroll
        for (int o = 32; o; o >>= 1) s += __shfl_xor(s, o, 64);
        if (tid == 0) sm.u.a.red[1] = 1.f / s;
      }
      __syncthreads();
      { // A5: ctx f-slice [qA*128, +128): l split 4-way, bf16 encB reads
        const int lgrp = tid >> 7, fl = tid & 127;
        const u16* eb = encB + ((size_t)bA * 196) * 512 + qA * 128 + fl;
        float a = 0.f;
#pragma unroll 7
        for (int i = 0; i < 49; ++i) {
          const int l = lgrp * 49 + i;
          a += sm.u.a.sc[l] * bf2f(eb[(size_t)l * 512]);
        }
        sm.u.a.ctxp[lgrp][fl] = a;
      }
      __syncthreads();
      if (tid < 128) {
        float v2 = ((sm.u.a.ctxp[0][tid] + sm.u.a.ctxp[1][tid]) +
                    (sm.u.a.ctxp[2][tid] + sm.u.a.ctxp[3][tid])) * sm.u.a.red[1];
        sm.u.a.ctxb[tid] = f2bf(v2);
      }
      __syncthreads();
      if (tid < 64) {
        unsigned pv = (unsigned)sm.u.a.ctxb[2 * tid] | ((unsigned)sm.u.a.ctxb[2 * tid + 1] << 16);
        st32_sys(xin + bA * 1024 + qA * 128 + 2 * tid, pv);
      }
      __syncthreads();                         // ctx stores drained
      if (tid == 0) stu_sys(ctxF + bA * 4 + qA, (unsigned)(t + 1));
    }

    // ============ phase B: gates for batches [bq*16,+16), jp [js*32,+32) ============
    // embp prefetch + W2p staging are independent of ctx/h -> issue before waits
    float epv;
    {
      const int bl = tid >> 5, jl = tid & 31;
      epv = embp[((size_t)((bq * 16 + bl) * 32 + t)) * 2048 + js * 32 + jl];
    }
#pragma unroll
    for (int i = 0; i < 8; ++i) {
      const int c = tid + i * 512;              // 32 rows x 128 chunks
      const int row = c >> 7, col8 = c & 127;
      s16x8 v = *(const s16x8*)(W2p + (size_t)(js * 32 + row) * 1024 + col8 * 8);
      *(s16x8*)((char*)sm.u.b.Bs + swz2(row, col8 * 16)) = v;
    }
    if (t > 0) {                               // wait ctx(t) and h(t) of my batches
      if (w == 0)      poll64(ctxF + bq * 64, (unsigned)(t + 1));
      else if (w == 1) poll64(hF + bq * 64, (unsigned)t);
    }
    __syncthreads();                           // waits done; phase-A LDS reads done
#pragma unroll
    for (int i = 0; i < 4; ++i) {
      const int c = tid + i * 512;              // 16 rows x 128 chunks
      const int row = c >> 7, col8 = c & 127;
      s16x8 v = ld8_sys(xin + (size_t)(bq * 16 + row) * 1024 + col8 * 8);
      *(s16x8*)((char*)sm.u.b.As + swz2(row, col8 * 16)) = v;
    }
    __syncthreads();
    { // MFMA: wave w = (kq = w>>1 K-quarter, ni = w&1 n-tile); 8 mfma each
      const int kq = w >> 1, ni = w & 1;
      f32x4 acc = {};
#pragma unroll
      for (int kk = 0; kk < 8; ++kk) {
        const int kcolB = (kq * 256 + kk * 32 + quad * 8) * 2;
        bf16x8 af = lds_frag((const u16*)((const char*)sm.u.b.As + swz2(lm, kcolB)));
        bf16x8 bf = lds_frag((const u16*)((const char*)sm.u.b.Bs + swz2(ni * 16 + lm, kcolB)));
        acc = __builtin_amdgcn_mfma_f32_16x16x32_bf16(af, bf, acc, 0, 0, 0);
      }
#pragma unroll
      for (int r = 0; r < 4; ++r)               // C/D: col=lane&15, row=quad*4+reg
        sm.u.b.gf[w][quad * 4 + r][lm] = acc[r];
    }
    __syncthreads();
    { // reduce K-quarters + embp
      const int bl = tid >> 5, jl = tid & 31;
      const int nn = jl >> 4, cc = jl & 15;
      float g = ((sm.u.b.gf[nn][bl][cc] + sm.u.b.gf[2 + nn][bl][cc]) +
                 (sm.u.b.gf[4 + nn][bl][cc] + sm.u.b.gf[6 + nn][bl][cc])) + epv;
      sm.u.b.gg[bl][jl] = g;
    }
    __syncthreads();
    if (tid < 128) {   // LSTM pointwise; c in register
      const int bl = tid >> 3, kl = tid & 7;
      const float gi = sm.u.b.gg[bl][kl * 4 + 0];
      const float gf_ = sm.u.b.gg[bl][kl * 4 + 1];
      const float ggv = sm.u.b.gg[bl][kl * 4 + 2];
      const float go = sm.u.b.gg[bl][kl * 4 + 3];
      c_reg = fsig(gf_) * c_reg + fsig(gi) * ftanh(ggv);
      const float h2 = fsig(go) * ftanh(c_reg);
      const u16 hb2 = f2bf(h2);
      const int bg = bq * 16 + bl, kg = js * 8 + kl;
      hs[(size_t)(bg * 32 + t) * 512 + kg] = hb2;   // normal store (post-kernel use)
      sm.u.b.hbl[bl][kl] = hb2;
    }
    __syncthreads();
    if (tid < 64) {    // pack h pairs -> sys store
      const int bl = tid >> 2, p = tid & 3;
      unsigned pv = (unsigned)sm.u.b.hbl[bl][2 * p] | ((unsigned)sm.u.b.hbl[bl][2 * p + 1] << 16);
      st32_sys(hout + (size_t)(bq * 16 + bl) * 1024 + 512 + js * 8 + 2 * p, pv);
    }
    __syncthreads();                           // h stores drained
    if (tid == 0) stu_sys(hF + blk, (unsigned)(t + 1));   // hF[bq*64+js] == hF[blk]
  }
}

// ---------------------------------------------------------------------------
// Scratch layout inside d_out (262 MB; all dead before the final fc GEMM):
// ---------------------------------------------------------------------------
static constexpr size_t OFF_ENCP = 0;                       // u16 [12544][512]
static constexpr size_t OFF_EMBP = 16777216;                // f32 [2048][2048]
static constexpr size_t OFF_EMBA = 33554432;                // u16 [2048][512]
static constexpr size_t OFF_WIHE = 35651584;                // u16 [2048][512]
static constexpr size_t OFF_W2P  = 37748736;                // u16 [2048][1024]
static constexpr size_t OFF_B2   = 41943040;                // f32 [2048]
static constexpr size_t OFF_XC0  = 41951232;                // u16 [2][64][1024]
static constexpr size_t OFF_WDP  = 42213376;                // u16 [64][512][8]
static constexpr size_t OFF_FLG  = 42737664;                // u32 [3][256] sync flags
static constexpr size_t OFF_SCP  = 42741760;                // f32 [64][4][256] partials
static constexpr size_t OFF_ENCB = 43003904;                // u16 [64][196][512]
// d_ws: hs (u16 [2048][512] = 2 MB) + dtype flag (int).

extern "C" void kernel_launch(void* const* d_in, const int* in_sizes, int n_in,
                              void* d_out, int out_size, void* d_ws, size_t ws_size,
                              hipStream_t stream) {
  const void* enc   = d_in[0];
  const int*  caps  = (const int*)d_in[1];
  const void* embed = d_in[2];
  const void* We    = d_in[3];
  const void* be    = d_in[4];
  const void* Wd    = d_in[5];
  const void* bd    = d_in[6];
  const void* vw    = d_in[7];
  // d_in[8] (v_b) unused: constant shift inside softmax
  const void* Wih   = d_in[9];
  const void* Whh   = d_in[10];
  const void* bih   = d_in[11];
  const void* bhh   = d_in[12];
  const void* Wf    = d_in[13];
  const void* bfv   = d_in[14];

  char* ob = (char*)d_out;
  u16*      encp   = (u16*)(ob + OFF_ENCP);
  float*    embp   = (float*)(ob + OFF_EMBP);
  u16*      embA   = (u16*)(ob + OFF_EMBA);
  u16*      WiheP  = (u16*)(ob + OFF_WIHE);
  u16*      W2p    = (u16*)(ob + OFF_W2P);
  float*    bias2  = (float*)(ob + OFF_B2);
  u16*      xbuf   = (u16*)(ob + OFF_XC0);
  u16*      WdP    = (u16*)(ob + OFF_WDP);
  unsigned* flags  = (unsigned*)(ob + OFF_FLG);
  float*    scp    = (float*)(ob + OFF_SCP);
  u16*      encB   = (u16*)(ob + OFF_ENCB);
  u16*      hs     = (u16*)d_ws;
  int*      flagp  = (int*)((char*)d_ws + 2048ull * 512 * 2);

  detect_kernel<<<1, 256, 0, stream>>>((const unsigned int*)embed, flagp, flags);
  pack_kernel<<<4096, 256, 0, stream>>>(caps, embed, Wih, Whh, bih, bhh, Wd, enc,
                                        WiheP, W2p, bias2, embA, WdP, encB, flagp);
  init_kernel<<<256, 256, 0, stream>>>(enc, xbuf, flagp);

  // enc_proj (bf16 scratch): [12544,512] x We[512,512] + be
  gemm_bt<<<dim3(4, 98), 256, 0, stream>>>(enc, We, be, encp, 512, 512, flagp, 2, 2, 2, 0, 0);
  // embproj (fp32 scratch): [2048,512] x WiheP[2048,512] + (b_ih+b_hh)
  gemm_bt<<<dim3(16, 16), 256, 0, stream>>>(embA, WiheP, bias2, embp, 2048, 512, flagp, 0, 0, 1, 1, 0);

  // all 32 timesteps in one persistent kernel, 256 blocks (1/CU)
  loop_kernel<<<256, 512, 0, stream>>>(encp, WdP, bd, vw, W2p, embp, encB,
                                       xbuf, hs, scp, flags, flagp);

  // fc head: [2048,512] x Wf[32000,512] + bf -> d_out [B,T,V] (XCD swizzle)
  gemm_bt<<<dim3(250, 16), 256, 0, stream>>>(hs, Wf, bfv, d_out, 32000, 512, flagp, 0, 2, 2, 2, 1);
}